// Round 11
// baseline (332.499 us; speedup 1.0000x reference)
//
#include <hip/hip_runtime.h>
#include <hip/hip_bf16.h>

#define PI_F 3.14159265f

// Flat index convention: state.reshape((2,)*16) => qubit q <-> flat bit j = 15-q.
// Per layer: Ry(all f), CNOT chain (15->14),(14->13),...,(1->0),(0->15), Rz(all f).
// Measurement <Z_q> q=0,1,2 -> flat bits 15,14,13.
//
// 2-pass structure (512KB/element canonical state st[f] in d_ws):
//   P1 k_all (outer=f13..15, 512 thr, 16 amps/thr, WRITE-only), R8-verified
//     algebra and gate code. Transposes run on a 32KB tile via THREAD-split
//     two-phase exchanges (split bit is a thread bit in BOTH layouts, so each
//     phase's writers==readers and reads land straight back into a[] — no
//     temp registers):
//       A->B, B->C: split f0 (t bit0);  C->D: split f7 (t bit3).
//     D->S is reg-split (f0 = i0 both sides, R10-verified addresses) with
//     nb[8] at end-of-kernel (tables dead).  All LDS patterns XOR-folded to
//     <=2-way bank aliasing (free).  LDS 64KB -> ~33.5KB => 4 blocks/CU.
//   P2 k_fin (outer=f10..12, 256 thr, READ-only, verbatim-verified):
//     CN2(0->15), Rz2(f15), Ry3{0,13,14,15}, measurement with CN3 transported:
//     Z_f15 -> parity(f0..f14); Z_f14 -> f14^f15; Z_f13 -> f13^f14^f15.
// Chunked at 256 elements (128MB) so the P1->P2 handoff is L3-resident.

__device__ __forceinline__ unsigned swz(unsigned l){ return l ^ ((l>>5)&31u); }
// bank-conflict folds (bijective: upper bits XORed into low-5)
__device__ __forceinline__ unsigned fold2(unsigned x){ return x ^ (((x>>6)&7u)<<2); }
__device__ __forceinline__ unsigned fold3(unsigned x){ return x ^ ((x>>4)&7u) ^ (((x>>7)&3u)<<3); }

__device__ __forceinline__ float2 cmul(float2 a, float2 b){
    return make_float2(a.x*b.x - a.y*b.y, a.x*b.y + a.y*b.x);
}

__device__ __forceinline__ void ry_pair(float2& A0, float2& A1, float c, float s){
    float2 a0=A0, a1=A1;
    A0 = make_float2(c*a0.x - s*a1.x, c*a0.y - s*a1.y);
    A1 = make_float2(s*a0.x + c*a1.x, s*a0.y + c*a1.y);
}

// ---------------- P1: full generation + layer2(- (0->15),Rz2(f15)) + Ry3(1..12)
__global__ __launch_bounds__(512, 8) void k_all(const float* __restrict__ xg,
                                                const float* __restrict__ pg,
                                                float2* __restrict__ st)
{
    __shared__ float2 tile[4096];   // 32KB
    __shared__ float cA[16], sA[16], cB[16], sB[16], cC[16], sC[16], phz1[16], phz2[16];
    __shared__ float2 K4[4], D1[16], E2A[16], E2B[8], E2C[8], E2D[8];
    const int tid = threadIdx.x;
    const int b = blockIdx.x >> 3;
    const unsigned outer = blockIdx.x & 7u;        // f13..15 (post-fold basis)

    // ---- stage 1: angle tables (R8 verbatim)
    if (tid < 16){
        int j = tid, q = 15 - j;
        float th = 0.5f*(xg[b*16+q]*PI_F + pg[q]);           // Ry1
        __sincosf(th, &sA[j], &cA[j]);
    } else if (tid < 32){
        int j = tid-16, q = 15 - j;
        float th = 0.5f*(xg[b*16+q]*PI_F + pg[32+q]);        // Ry2
        __sincosf(th, &sB[j], &cB[j]);
    } else if (tid < 48){
        int j = tid-32, q = 15 - j;
        float th = 0.5f*(xg[b*16+q]*PI_F + pg[64+q]);        // Ry3
        __sincosf(th, &sC[j], &cC[j]);
    } else if (tid < 64){
        int j = tid-48, q = 15 - j;
        phz1[j] = 0.5f*pg[16+q];                              // Rz1
    } else if (tid < 80){
        int j = tid-64, q = 15 - j;
        phz2[j] = 0.5f*pg[48+q];                              // Rz2
    }
    __syncthreads();
    // ---- stage 2: block-uniform tables (R6/R8-verified)
    if (tid < 4){
        const unsigned o13=outer&1u, o14=(outer>>1)&1u, o15=(outer>>2)&1u;
        const unsigned h13=o13^o14, h14=o14^o15, h15=o15;
        const int f0b=(tid>>1)&1, f12b=tid&1;
        float Kr=0.f, Ki=0.f;
        #pragma unroll
        for (int g=0; g<8; ++g){
            const unsigned g13=g&1u, g14=(g>>1)&1u, g15=(g>>2)&1u;
            float w;
            w  = (h13==g13)? cB[13] : (h13? sB[13] : -sB[13]);
            w *= (h14==g14)? cB[14] : (h14? sB[14] : -sB[14]);
            w *= (h15==g15)? cB[15] : (h15? sB[15] : -sB[15]);
            w *= (f12b^(int)g13)?          sA[12]:cA[12];
            w *= ((int)(g13^g14))?         sA[13]:cA[13];
            w *= ((int)g14^f0b^(int)g15)?  sA[14]:cA[14];
            w *= (f0b^(int)g15)?           sA[15]:cA[15];
            float phg = (g13? phz1[13]:-phz1[13]) + (g14? phz1[14]:-phz1[14])
                      + (g15? phz1[15]:-phz1[15]);
            float sn,cs; __sincosf(phg,&sn,&cs);
            Kr += w*cs; Ki += w*sn;
        }
        K4[tid] = make_float2(Kr,Ki);
    } else if (tid>=16 && tid<32){
        const int ii = tid-16;  // Rz1 deltas over f9..12
        float d=0.f;
        #pragma unroll
        for (int j=0;j<4;j++) d += ((ii>>j)&1)? phz1[9+j]:-phz1[9+j];
        float sn,cs; __sincosf(d,&sn,&cs); D1[ii]=make_float2(cs,sn);
    } else if (tid>=32 && tid<48){
        const int ii = tid-32;  // Rz2 over f9..12
        float d=0.f;
        #pragma unroll
        for (int j=0;j<4;j++) d += ((ii>>j)&1)? phz2[9+j]:-phz2[9+j];
        float sn,cs; __sincosf(d,&sn,&cs); E2A[ii]=make_float2(cs,sn);
    } else if (tid>=48 && tid<56){
        const int ii = tid-48;  // Rz2 over f6..8
        float d=0.f;
        #pragma unroll
        for (int j=0;j<3;j++) d += ((ii>>j)&1)? phz2[6+j]:-phz2[6+j];
        float sn,cs; __sincosf(d,&sn,&cs); E2B[ii]=make_float2(cs,sn);
    } else if (tid>=56 && tid<64){
        const int ii = tid-56;  // Rz2 over f3..5
        float d=0.f;
        #pragma unroll
        for (int j=0;j<3;j++) d += ((ii>>j)&1)? phz2[3+j]:-phz2[3+j];
        float sn,cs; __sincosf(d,&sn,&cs); E2C[ii]=make_float2(cs,sn);
    } else if (tid>=64 && tid<72){
        const int ii = tid-64;  // Rz2 over f0..2 + uniform f13,f14
        float d=0.f;
        #pragma unroll
        for (int j=0;j<3;j++) d += ((ii>>j)&1)? phz2[j]:-phz2[j];
        d += (outer&1u)?      phz2[13]:-phz2[13];
        d += ((outer>>1)&1u)? phz2[14]:-phz2[14];
        float sn,cs; __sincosf(d,&sn,&cs); E2D[ii]=make_float2(cs,sn);
    }
    __syncthreads();

    const unsigned t = tid;                 // trip A: t bits 0..8 = f0..8
    float2 a[16];
    // ---- Trip A generation: i = f9..12  (R8-verified, verbatim)
    {
        float base_t = 1.0f;
        #pragma unroll
        for (int j=0;j<8;j++){
            int v = (int)(((t>>j)^(t>>(j+1)))&1u);           // b_pre[j]=f_j^f_{j+1}
            base_t *= v? sA[j]:cA[j];
        }
        float pht = 0.f;
        #pragma unroll
        for (int j=0;j<9;j++) pht += ((t>>j)&1u)? phz1[j]:-phz1[j];
        float Ety,Etx; __sincosf(pht,&Ety,&Etx);
        const float2 Et = make_float2(Etx,Ety);
        const unsigned t0 = t&1u;
        const float2 EK0 = cmul(Et, K4[t0<<1]);
        const float2 EK1 = cmul(Et, K4[(t0<<1)|1u]);
        const int t8 = (int)((t>>8)&1u);
        #pragma unroll
        for (int i=0;i<16;i++){
            const int i0=i&1, i1=(i>>1)&1, i2=(i>>2)&1, i3=(i>>3)&1;
            float pr = base_t;
            pr *= (t8^i0)? sA[8] :cA[8];                     // b_pre[8]=f8^f9
            pr *= (i0^i1)? sA[9] :cA[9];
            pr *= (i1^i2)? sA[10]:cA[10];
            pr *= (i2^i3)? sA[11]:cA[11];
            float2 w = cmul(D1[i], i3? EK1:EK0);
            a[i] = make_float2(pr*w.x, pr*w.y);
        }
    }
    // Trip A gates (R8 verbatim): i0=f9,i1=f10,i2=f11,i3=f12
    #pragma unroll
    for (int j=0;j<16;j++){ if (j&1)  continue; ry_pair(a[j],a[j|1] ,cB[9] ,sB[9]);  }
    #pragma unroll
    for (int j=0;j<16;j++){ if (j&2)  continue; ry_pair(a[j],a[j|2] ,cB[10],sB[10]); }
    #pragma unroll
    for (int j=0;j<16;j++){ if (j&4)  continue; ry_pair(a[j],a[j|4] ,cB[11],sB[11]); }
    #pragma unroll
    for (int j=0;j<16;j++){ if (j&8)  continue; ry_pair(a[j],a[j|8] ,cB[12],sB[12]); }
    if (outer & 1u){  // CN2(13->12): ctrl f13=o13 (uniform), tgt i3
        #pragma unroll
        for (int j=0;j<16;j++){ if (j&8) continue; float2 tm=a[j]; a[j]=a[j|8]; a[j|8]=tm; }
    }
    #pragma unroll
    for (int j=0;j<16;j++){ if (j&4) continue; if ((j>>3)&1){ float2 tm=a[j]; a[j]=a[j|4]; a[j|4]=tm; } } // (12->11)
    #pragma unroll
    for (int j=0;j<16;j++){ if (j&2) continue; if ((j>>2)&1){ float2 tm=a[j]; a[j]=a[j|2]; a[j|2]=tm; } } // (11->10)
    #pragma unroll
    for (int j=0;j<16;j++){ if (j&1) continue; if ((j>>1)&1){ float2 tm=a[j]; a[j]=a[j|1]; a[j|1]=tm; } } // (10->9)
    #pragma unroll
    for (int i=0;i<16;i++) a[i] = cmul(a[i], E2A[i]);        // Rz2(f9..12)
    #pragma unroll
    for (int j=0;j<16;j++){ if (j&2)  continue; ry_pair(a[j],a[j|2] ,cC[10],sC[10]); }
    #pragma unroll
    for (int j=0;j<16;j++){ if (j&4)  continue; ry_pair(a[j],a[j|4] ,cC[11],sC[11]); }
    #pragma unroll
    for (int j=0;j<16;j++){ if (j&8)  continue; ry_pair(a[j],a[j|8] ,cC[12],sC[12]); }

    // ---- transpose A -> B: thread-split on f0 (t bit0).  addr = f1..f12 packed:
    //   A-coords:  (t>>1)[f1..8] | i<<8[f9..12]
    //   B-coords:  ((t&63)>>1)[f1..5] | n<<5[f6..9] | (t>>6)<<9[f10..12]
    {
        if (!(t & 1u)){
            #pragma unroll
            for (int i=0;i<16;i++) tile[(t>>1) | ((unsigned)i<<8)] = a[i];
        }
        __syncthreads();
        if (!(t & 1u)){
            #pragma unroll
            for (int n=0;n<16;n++) a[n] = tile[((t&63u)>>1) | ((unsigned)n<<5) | ((t>>6)<<9)];
        }
        __syncthreads();
        if (t & 1u){
            #pragma unroll
            for (int i=0;i<16;i++) tile[(t>>1) | ((unsigned)i<<8)] = a[i];
        }
        __syncthreads();
        if (t & 1u){
            #pragma unroll
            for (int n=0;n<16;n++) a[n] = tile[((t&63u)>>1) | ((unsigned)n<<5) | ((t>>6)<<9)];
        }
    }
    // Trip B (R8 verbatim): i0=f6,i1=f7,i2=f8,i3=f9 ; t0=f0..t5=f5, t6..8=f10..12
    #pragma unroll
    for (int j=0;j<16;j++){ if (j&1) continue; ry_pair(a[j],a[j|1],cB[6],sB[6]); }
    #pragma unroll
    for (int j=0;j<16;j++){ if (j&2) continue; ry_pair(a[j],a[j|2],cB[7],sB[7]); }
    #pragma unroll
    for (int j=0;j<16;j++){ if (j&4) continue; ry_pair(a[j],a[j|4],cB[8],sB[8]); }
    #pragma unroll
    for (int j=0;j<16;j++){ if (j&4) continue; if ((j>>3)&1){ float2 tm=a[j]; a[j]=a[j|4]; a[j|4]=tm; } } // (9->8)
    #pragma unroll
    for (int j=0;j<16;j++){ if (j&2) continue; if ((j>>2)&1){ float2 tm=a[j]; a[j]=a[j|2]; a[j|2]=tm; } } // (8->7)
    #pragma unroll
    for (int j=0;j<16;j++){ if (j&1) continue; if ((j>>1)&1){ float2 tm=a[j]; a[j]=a[j|1]; a[j|1]=tm; } } // (7->6)
    #pragma unroll
    for (int i=0;i<16;i++) a[i] = cmul(a[i], E2B[i&7]);      // Rz2(f6..8)
    #pragma unroll
    for (int j=0;j<16;j++){ if (j&2) continue; ry_pair(a[j],a[j|2],cC[7],sC[7]); }
    #pragma unroll
    for (int j=0;j<16;j++){ if (j&4) continue; ry_pair(a[j],a[j|4],cC[8],sC[8]); }
    #pragma unroll
    for (int j=0;j<16;j++){ if (j&8) continue; ry_pair(a[j],a[j|8],cC[9],sC[9]); }

    // ---- transpose B -> C: thread-split f0; fold2 on both sides.
    //   B-coords: ((t&63)>>1)[f1..5] | i<<5[f6..9] | (t>>6)<<9[f10..12]
    //   C-coords: ((t>>1)&3)[f1,f2] | n<<2[f3..6] | (t>>3)<<6[f7..12]
    {
        __syncthreads();
        if (!(t & 1u)){
            #pragma unroll
            for (int i=0;i<16;i++) tile[fold2(((t&63u)>>1) | ((unsigned)i<<5) | ((t>>6)<<9))] = a[i];
        }
        __syncthreads();
        if (!(t & 1u)){
            #pragma unroll
            for (int n=0;n<16;n++) a[n] = tile[fold2(((t>>1)&3u) | ((unsigned)n<<2) | ((t>>3)<<6))];
        }
        __syncthreads();
        if (t & 1u){
            #pragma unroll
            for (int i=0;i<16;i++) tile[fold2(((t&63u)>>1) | ((unsigned)i<<5) | ((t>>6)<<9))] = a[i];
        }
        __syncthreads();
        if (t & 1u){
            #pragma unroll
            for (int n=0;n<16;n++) a[n] = tile[fold2(((t>>1)&3u) | ((unsigned)n<<2) | ((t>>3)<<6))];
        }
    }
    // Trip C (R8 verbatim): i0=f3,i1=f4,i2=f5,i3=f6 ; t0..2=f0..2, t3..8=f7..12
    #pragma unroll
    for (int j=0;j<16;j++){ if (j&1) continue; ry_pair(a[j],a[j|1],cB[3],sB[3]); }
    #pragma unroll
    for (int j=0;j<16;j++){ if (j&2) continue; ry_pair(a[j],a[j|2],cB[4],sB[4]); }
    #pragma unroll
    for (int j=0;j<16;j++){ if (j&4) continue; ry_pair(a[j],a[j|4],cB[5],sB[5]); }
    #pragma unroll
    for (int j=0;j<16;j++){ if (j&4) continue; if ((j>>3)&1){ float2 tm=a[j]; a[j]=a[j|4]; a[j|4]=tm; } } // (6->5)
    #pragma unroll
    for (int j=0;j<16;j++){ if (j&2) continue; if ((j>>2)&1){ float2 tm=a[j]; a[j]=a[j|2]; a[j|2]=tm; } } // (5->4)
    #pragma unroll
    for (int j=0;j<16;j++){ if (j&1) continue; if ((j>>1)&1){ float2 tm=a[j]; a[j]=a[j|1]; a[j|1]=tm; } } // (4->3)
    #pragma unroll
    for (int i=0;i<16;i++) a[i] = cmul(a[i], E2C[i&7]);      // Rz2(f3..5)
    #pragma unroll
    for (int j=0;j<16;j++){ if (j&2) continue; ry_pair(a[j],a[j|2],cC[4],sC[4]); }
    #pragma unroll
    for (int j=0;j<16;j++){ if (j&4) continue; ry_pair(a[j],a[j|4],cC[5],sC[5]); }
    #pragma unroll
    for (int j=0;j<16;j++){ if (j&8) continue; ry_pair(a[j],a[j|8],cC[6],sC[6]); }

    // ---- transpose C -> D: thread-split f7 (t bit3); fold3 both sides.
    //   C-coords: (t&7)[f0..2] | i<<3[f3..6] | (t>>4)<<7[f8..12]
    //   D-coords: n[f0..3] | (t&7)<<4[f4..6] | (t>>4)<<7[f8..12]
    {
        __syncthreads();
        if (!((t>>3) & 1u)){
            #pragma unroll
            for (int i=0;i<16;i++) tile[fold3((t&7u) | ((unsigned)i<<3) | ((t>>4)<<7))] = a[i];
        }
        __syncthreads();
        if (!((t>>3) & 1u)){
            #pragma unroll
            for (int n=0;n<16;n++) a[n] = tile[fold3((unsigned)n | ((t&7u)<<4) | ((t>>4)<<7))];
        }
        __syncthreads();
        if ((t>>3) & 1u){
            #pragma unroll
            for (int i=0;i<16;i++) tile[fold3((t&7u) | ((unsigned)i<<3) | ((t>>4)<<7))] = a[i];
        }
        __syncthreads();
        if ((t>>3) & 1u){
            #pragma unroll
            for (int n=0;n<16;n++) a[n] = tile[fold3((unsigned)n | ((t&7u)<<4) | ((t>>4)<<7))];
        }
    }
    // Trip D (R8 verbatim): i0=f0,i1=f1,i2=f2,i3=f3 ; t0..8=f4..12
    #pragma unroll
    for (int j=0;j<16;j++){ if (j&1) continue; ry_pair(a[j],a[j|1],cB[0],sB[0]); }
    #pragma unroll
    for (int j=0;j<16;j++){ if (j&2) continue; ry_pair(a[j],a[j|2],cB[1],sB[1]); }
    #pragma unroll
    for (int j=0;j<16;j++){ if (j&4) continue; ry_pair(a[j],a[j|4],cB[2],sB[2]); }
    #pragma unroll
    for (int j=0;j<16;j++){ if (j&4) continue; if ((j>>3)&1){ float2 tm=a[j]; a[j]=a[j|4]; a[j|4]=tm; } } // (3->2)
    #pragma unroll
    for (int j=0;j<16;j++){ if (j&2) continue; if ((j>>2)&1){ float2 tm=a[j]; a[j]=a[j|2]; a[j|2]=tm; } } // (2->1)
    #pragma unroll
    for (int j=0;j<16;j++){ if (j&1) continue; if ((j>>1)&1){ float2 tm=a[j]; a[j]=a[j|1]; a[j|1]=tm; } } // (1->0)
    #pragma unroll
    for (int i=0;i<16;i++) a[i] = cmul(a[i], E2D[i&7]);      // Rz2(f0..2,f13,f14)
    #pragma unroll
    for (int j=0;j<16;j++){ if (j&2) continue; ry_pair(a[j],a[j|2],cC[1],sC[1]); }
    #pragma unroll
    for (int j=0;j<16;j++){ if (j&4) continue; ry_pair(a[j],a[j|4],cC[2],sC[2]); }
    #pragma unroll
    for (int j=0;j<16;j++){ if (j&8) continue; ry_pair(a[j],a[j|8],cC[3],sC[3]); }

    // ---- transpose D -> store layout: reg-split on f0 (R10-verified addresses),
    //   nb[8] + phase-1 reads straight into odd a-slots.
    //   D write: swz((i>>1)[f1..3] | (t<<3)[f4..12])
    //   S read:  swz((k&1)[f1] | (t<<1)[f2..10] | (k>>1)<<10[f11,f12]); n=(k<<1)|phase
    {
        float2 nb[8];
        __syncthreads();
        #pragma unroll
        for (int i=0;i<16;i+=2) tile[swz((unsigned)(i>>1) | (t<<3))] = a[i];      // f0=0
        __syncthreads();
        #pragma unroll
        for (int k=0;k<8;k++) nb[k] = tile[swz((unsigned)(k&1) | (t<<1) | ((unsigned)(k>>1)<<10))];
        __syncthreads();
        #pragma unroll
        for (int i=1;i<16;i+=2) tile[swz((unsigned)(i>>1) | (t<<3))] = a[i];      // f0=1
        __syncthreads();
        #pragma unroll
        for (int k=0;k<8;k++) a[(k<<1)|1] = tile[swz((unsigned)(k&1) | (t<<1) | ((unsigned)(k>>1)<<10))];
        #pragma unroll
        for (int k=0;k<8;k++) a[k<<1] = nb[k];
    }
    // ---- coalesced store (R10-verified): f = (t<<2)|(u<<11); n: f0,f1,f11,f12
    float2* sp = st + ((size_t)b<<16);
    #pragma unroll
    for (int u=0;u<4;u++){
        float4* d4 = (float4*)(sp + ((t<<2) | ((unsigned)u<<11) | (outer<<13)));
        d4[0]=make_float4(a[4*u+0].x,a[4*u+0].y,a[4*u+1].x,a[4*u+1].y);
        d4[1]=make_float4(a[4*u+2].x,a[4*u+2].y,a[4*u+3].x,a[4*u+3].y);
    }
}

// ---------------- P2 k_fin (B-type, outer = f10..12, READ, no LDS tile) — verbatim
__global__ __launch_bounds__(256) void k_fin(const float* __restrict__ xg,
                                             const float* __restrict__ pg,
                                             const float2* __restrict__ st,
                                             float* __restrict__ outg)
{
    __shared__ float cN[16], sN[16];
    __shared__ float snp, csp;
    __shared__ float red[4][3];
    const int tid = threadIdx.x;
    const int b = blockIdx.x >> 3;
    const unsigned outer = blockIdx.x & 7u;        // f bits 10..12
    if (tid < 16){
        int j=tid, q=15-j;
        float th = 0.5f*(xg[b*16+q]*PI_F + pg[64 + q]);      // Ry3
        float s,c; __sincosf(th,&s,&c);
        cN[j]=c; sN[j]=s;
    }
    if (tid==16){ float phi = 0.5f*pg[48 + 0]; float s,c; __sincosf(phi,&s,&c); snp=s; csp=c; }
    __syncthreads();
    const unsigned t = tid;
    const float2* sp = st + ((size_t)b<<16);
    float2 a[32];
    #pragma unroll
    for (int u=0;u<8;u++){
        unsigned fb = (t<<2) | (outer<<10) | ((unsigned)u<<13);
        const float4* s4 = (const float4*)(sp + fb);
        float4 v0=s4[0], v1=s4[1];
        a[4*u+0]=make_float2(v0.x,v0.y); a[4*u+1]=make_float2(v0.z,v0.w);
        a[4*u+2]=make_float2(v1.x,v1.y); a[4*u+3]=make_float2(v1.z,v1.w);
    }
    // CN2(0->15): ctrl f0 = i0, tgt f15 = i4
    #pragma unroll
    for (int j=0;j<32;j++){ if (j&16) continue; if (j&1){ float2 tm=a[j]; a[j]=a[j|16]; a[j|16]=tm; } }
    // Rz2(f15)
    #pragma unroll
    for (int j=0;j<32;j++){
        float sn = ((j>>4)&1)? snp : -snp;
        float2 v=a[j];
        a[j]=make_float2(v.x*csp - v.y*sn, v.x*sn + v.y*csp);
    }
    #pragma unroll
    for (int j=0;j<32;j++){ if (j&1)  continue; ry_pair(a[j],a[j|1] ,cN[0] ,sN[0]);  }
    #pragma unroll
    for (int j=0;j<32;j++){ if (j&4)  continue; ry_pair(a[j],a[j|4] ,cN[13],sN[13]); }
    #pragma unroll
    for (int j=0;j<32;j++){ if (j&8)  continue; ry_pair(a[j],a[j|8] ,cN[14],sN[14]); }
    #pragma unroll
    for (int j=0;j<32;j++){ if (j&16) continue; ry_pair(a[j],a[j|16],cN[15],sN[15]); }
    const int pto = (__popc(t) + __popc(outer)) & 1;   // parity(f2..f12)
    float v0=0.f, v1=0.f, v2=0.f;
    #pragma unroll
    for (int i=0;i<32;i++){
        const int i0=i&1, i1=(i>>1)&1, i2=(i>>2)&1, i3=(i>>3)&1, i4=(i>>4)&1;
        const float pr = a[i].x*a[i].x + a[i].y*a[i].y;
        v0 += (i0^i1^i2^i3^pto)? -pr : pr;   // parity(f0..f14)
        v1 += (i3^i4)?           -pr : pr;   // f14^f15
        v2 += (i2^i3^i4)?        -pr : pr;   // f13^f14^f15
    }
    #pragma unroll
    for (int off=32; off>0; off>>=1){
        v0 += __shfl_down(v0, off);
        v1 += __shfl_down(v1, off);
        v2 += __shfl_down(v2, off);
    }
    const int wv = tid>>6, ln = tid&63;
    if (ln==0){ red[wv][0]=v0; red[wv][1]=v1; red[wv][2]=v2; }
    __syncthreads();
    if (tid<3){
        float s = red[0][tid]+red[1][tid]+red[2][tid]+red[3][tid];
        atomicAdd(&outg[b*3+tid], s);
    }
}

extern "C" void kernel_launch(void* const* d_in, const int* in_sizes, int n_in,
                              void* d_out, int out_size, void* d_ws, size_t ws_size,
                              hipStream_t stream)
{
    const float* x = (const float*)d_in[0];
    const float* params = (const float*)d_in[1];
    float* out = (float*)d_out;
    float2* st = (float2*)d_ws;
    const int B = in_sizes[0] / 16;

    hipMemsetAsync(d_out, 0, (size_t)out_size*sizeof(float), stream);

    const size_t per = (size_t)65536 * sizeof(float2);   // 512 KB per batch element
    int chunk = (int)(ws_size / per);
    if (chunk > 256) chunk = 256;                        // 128 MB -> L3-resident handoff
    if (chunk < 1) chunk = 1;
    if (chunk > B) chunk = B;
    for (int b0=0; b0<B; b0+=chunk){
        const int nb = (B-b0 < chunk) ? (B-b0) : chunk;
        const float* xb = x + (size_t)b0*16;
        float* ob = out + (size_t)b0*3;
        hipLaunchKernelGGL(k_all, dim3(nb*8), dim3(512), 0, stream, xb, params, st);
        hipLaunchKernelGGL(k_fin, dim3(nb*8), dim3(256), 0, stream, xb, params, st, ob);
    }
}

// Round 12
// 238.071 us; speedup vs baseline: 1.3966x; 1.3966x over previous
//
#include <hip/hip_runtime.h>
#include <hip/hip_bf16.h>

#define PI_F 3.14159265f

// Flat index convention: state.reshape((2,)*16) => qubit q <-> flat bit j = 15-q.
// Per layer: Ry(all f), CNOT chain (15->14),(14->13),...,(1->0),(0->15), Rz(all f).
// Measurement <Z_q> q=0,1,2 -> flat bits 15,14,13.
//
// 2-pass structure (512KB/element canonical state st[f] in d_ws):
//   P1 k_all (outer=f13..15, 512 thr, 16 amps/thr, WRITE-only), R8-verified
//     algebra and gate code; R11-verified 32KB thread-split transposes.
//     LAUNCH BOUNDS (512,4): R9-R11 showed min-waves=8 makes the compiler
//     clamp to 32 VGPR -> scratch spill (FETCH 150MB + WRITE 510MB phantom
//     traffic).  (512,4) allocates ~56 (R8) <= 64, so HW still reaches
//     4 blocks/CU via the 33.8KB LDS without any spill.
//   P2 k_fin (outer=f10..12, 256 thr, READ-only, verbatim-verified).
// Chunked at 256 elements (128MB) so the P1->P2 handoff is L3-resident.

__device__ __forceinline__ unsigned swz(unsigned l){ return l ^ ((l>>5)&31u); }
// bank-conflict folds (bijective: upper bits XORed into low-5)
__device__ __forceinline__ unsigned fold2(unsigned x){ return x ^ (((x>>6)&7u)<<2); }
__device__ __forceinline__ unsigned fold3(unsigned x){ return x ^ ((x>>4)&7u) ^ (((x>>7)&3u)<<3); }

__device__ __forceinline__ float2 cmul(float2 a, float2 b){
    return make_float2(a.x*b.x - a.y*b.y, a.x*b.y + a.y*b.x);
}

__device__ __forceinline__ void ry_pair(float2& A0, float2& A1, float c, float s){
    float2 a0=A0, a1=A1;
    A0 = make_float2(c*a0.x - s*a1.x, c*a0.y - s*a1.y);
    A1 = make_float2(s*a0.x + c*a1.x, s*a0.y + c*a1.y);
}

// ---------------- P1: full generation + layer2(- (0->15),Rz2(f15)) + Ry3(1..12)
__global__ __launch_bounds__(512, 4) void k_all(const float* __restrict__ xg,
                                                const float* __restrict__ pg,
                                                float2* __restrict__ st)
{
    __shared__ float2 tile[4096];   // 32KB
    __shared__ float cA[16], sA[16], cB[16], sB[16], cC[16], sC[16], phz1[16], phz2[16];
    __shared__ float2 K4[4], D1[16], E2A[16], E2B[8], E2C[8], E2D[8];
    const int tid = threadIdx.x;
    const int b = blockIdx.x >> 3;
    const unsigned outer = blockIdx.x & 7u;        // f13..15 (post-fold basis)

    // ---- stage 1: angle tables (R8 verbatim)
    if (tid < 16){
        int j = tid, q = 15 - j;
        float th = 0.5f*(xg[b*16+q]*PI_F + pg[q]);           // Ry1
        __sincosf(th, &sA[j], &cA[j]);
    } else if (tid < 32){
        int j = tid-16, q = 15 - j;
        float th = 0.5f*(xg[b*16+q]*PI_F + pg[32+q]);        // Ry2
        __sincosf(th, &sB[j], &cB[j]);
    } else if (tid < 48){
        int j = tid-32, q = 15 - j;
        float th = 0.5f*(xg[b*16+q]*PI_F + pg[64+q]);        // Ry3
        __sincosf(th, &sC[j], &cC[j]);
    } else if (tid < 64){
        int j = tid-48, q = 15 - j;
        phz1[j] = 0.5f*pg[16+q];                              // Rz1
    } else if (tid < 80){
        int j = tid-64, q = 15 - j;
        phz2[j] = 0.5f*pg[48+q];                              // Rz2
    }
    __syncthreads();
    // ---- stage 2: block-uniform tables (R6/R8-verified)
    if (tid < 4){
        const unsigned o13=outer&1u, o14=(outer>>1)&1u, o15=(outer>>2)&1u;
        const unsigned h13=o13^o14, h14=o14^o15, h15=o15;
        const int f0b=(tid>>1)&1, f12b=tid&1;
        float Kr=0.f, Ki=0.f;
        #pragma unroll
        for (int g=0; g<8; ++g){
            const unsigned g13=g&1u, g14=(g>>1)&1u, g15=(g>>2)&1u;
            float w;
            w  = (h13==g13)? cB[13] : (h13? sB[13] : -sB[13]);
            w *= (h14==g14)? cB[14] : (h14? sB[14] : -sB[14]);
            w *= (h15==g15)? cB[15] : (h15? sB[15] : -sB[15]);
            w *= (f12b^(int)g13)?          sA[12]:cA[12];
            w *= ((int)(g13^g14))?         sA[13]:cA[13];
            w *= ((int)g14^f0b^(int)g15)?  sA[14]:cA[14];
            w *= (f0b^(int)g15)?           sA[15]:cA[15];
            float phg = (g13? phz1[13]:-phz1[13]) + (g14? phz1[14]:-phz1[14])
                      + (g15? phz1[15]:-phz1[15]);
            float sn,cs; __sincosf(phg,&sn,&cs);
            Kr += w*cs; Ki += w*sn;
        }
        K4[tid] = make_float2(Kr,Ki);
    } else if (tid>=16 && tid<32){
        const int ii = tid-16;  // Rz1 deltas over f9..12
        float d=0.f;
        #pragma unroll
        for (int j=0;j<4;j++) d += ((ii>>j)&1)? phz1[9+j]:-phz1[9+j];
        float sn,cs; __sincosf(d,&sn,&cs); D1[ii]=make_float2(cs,sn);
    } else if (tid>=32 && tid<48){
        const int ii = tid-32;  // Rz2 over f9..12
        float d=0.f;
        #pragma unroll
        for (int j=0;j<4;j++) d += ((ii>>j)&1)? phz2[9+j]:-phz2[9+j];
        float sn,cs; __sincosf(d,&sn,&cs); E2A[ii]=make_float2(cs,sn);
    } else if (tid>=48 && tid<56){
        const int ii = tid-48;  // Rz2 over f6..8
        float d=0.f;
        #pragma unroll
        for (int j=0;j<3;j++) d += ((ii>>j)&1)? phz2[6+j]:-phz2[6+j];
        float sn,cs; __sincosf(d,&sn,&cs); E2B[ii]=make_float2(cs,sn);
    } else if (tid>=56 && tid<64){
        const int ii = tid-56;  // Rz2 over f3..5
        float d=0.f;
        #pragma unroll
        for (int j=0;j<3;j++) d += ((ii>>j)&1)? phz2[3+j]:-phz2[3+j];
        float sn,cs; __sincosf(d,&sn,&cs); E2C[ii]=make_float2(cs,sn);
    } else if (tid>=64 && tid<72){
        const int ii = tid-64;  // Rz2 over f0..2 + uniform f13,f14
        float d=0.f;
        #pragma unroll
        for (int j=0;j<3;j++) d += ((ii>>j)&1)? phz2[j]:-phz2[j];
        d += (outer&1u)?      phz2[13]:-phz2[13];
        d += ((outer>>1)&1u)? phz2[14]:-phz2[14];
        float sn,cs; __sincosf(d,&sn,&cs); E2D[ii]=make_float2(cs,sn);
    }
    __syncthreads();

    const unsigned t = tid;                 // trip A: t bits 0..8 = f0..8
    float2 a[16];
    // ---- Trip A generation: i = f9..12  (R8-verified, verbatim)
    {
        float base_t = 1.0f;
        #pragma unroll
        for (int j=0;j<8;j++){
            int v = (int)(((t>>j)^(t>>(j+1)))&1u);           // b_pre[j]=f_j^f_{j+1}
            base_t *= v? sA[j]:cA[j];
        }
        float pht = 0.f;
        #pragma unroll
        for (int j=0;j<9;j++) pht += ((t>>j)&1u)? phz1[j]:-phz1[j];
        float Ety,Etx; __sincosf(pht,&Ety,&Etx);
        const float2 Et = make_float2(Etx,Ety);
        const unsigned t0 = t&1u;
        const float2 EK0 = cmul(Et, K4[t0<<1]);
        const float2 EK1 = cmul(Et, K4[(t0<<1)|1u]);
        const int t8 = (int)((t>>8)&1u);
        #pragma unroll
        for (int i=0;i<16;i++){
            const int i0=i&1, i1=(i>>1)&1, i2=(i>>2)&1, i3=(i>>3)&1;
            float pr = base_t;
            pr *= (t8^i0)? sA[8] :cA[8];                     // b_pre[8]=f8^f9
            pr *= (i0^i1)? sA[9] :cA[9];
            pr *= (i1^i2)? sA[10]:cA[10];
            pr *= (i2^i3)? sA[11]:cA[11];
            float2 w = cmul(D1[i], i3? EK1:EK0);
            a[i] = make_float2(pr*w.x, pr*w.y);
        }
    }
    // Trip A gates (R8 verbatim): i0=f9,i1=f10,i2=f11,i3=f12
    #pragma unroll
    for (int j=0;j<16;j++){ if (j&1)  continue; ry_pair(a[j],a[j|1] ,cB[9] ,sB[9]);  }
    #pragma unroll
    for (int j=0;j<16;j++){ if (j&2)  continue; ry_pair(a[j],a[j|2] ,cB[10],sB[10]); }
    #pragma unroll
    for (int j=0;j<16;j++){ if (j&4)  continue; ry_pair(a[j],a[j|4] ,cB[11],sB[11]); }
    #pragma unroll
    for (int j=0;j<16;j++){ if (j&8)  continue; ry_pair(a[j],a[j|8] ,cB[12],sB[12]); }
    if (outer & 1u){  // CN2(13->12): ctrl f13=o13 (uniform), tgt i3
        #pragma unroll
        for (int j=0;j<16;j++){ if (j&8) continue; float2 tm=a[j]; a[j]=a[j|8]; a[j|8]=tm; }
    }
    #pragma unroll
    for (int j=0;j<16;j++){ if (j&4) continue; if ((j>>3)&1){ float2 tm=a[j]; a[j]=a[j|4]; a[j|4]=tm; } } // (12->11)
    #pragma unroll
    for (int j=0;j<16;j++){ if (j&2) continue; if ((j>>2)&1){ float2 tm=a[j]; a[j]=a[j|2]; a[j|2]=tm; } } // (11->10)
    #pragma unroll
    for (int j=0;j<16;j++){ if (j&1) continue; if ((j>>1)&1){ float2 tm=a[j]; a[j]=a[j|1]; a[j|1]=tm; } } // (10->9)
    #pragma unroll
    for (int i=0;i<16;i++) a[i] = cmul(a[i], E2A[i]);        // Rz2(f9..12)
    #pragma unroll
    for (int j=0;j<16;j++){ if (j&2)  continue; ry_pair(a[j],a[j|2] ,cC[10],sC[10]); }
    #pragma unroll
    for (int j=0;j<16;j++){ if (j&4)  continue; ry_pair(a[j],a[j|4] ,cC[11],sC[11]); }
    #pragma unroll
    for (int j=0;j<16;j++){ if (j&8)  continue; ry_pair(a[j],a[j|8] ,cC[12],sC[12]); }

    // ---- transpose A -> B: thread-split on f0 (t bit0).  addr = f1..f12 packed:
    //   A-coords:  (t>>1)[f1..8] | i<<8[f9..12]
    //   B-coords:  ((t&63)>>1)[f1..5] | n<<5[f6..9] | (t>>6)<<9[f10..12]
    {
        if (!(t & 1u)){
            #pragma unroll
            for (int i=0;i<16;i++) tile[(t>>1) | ((unsigned)i<<8)] = a[i];
        }
        __syncthreads();
        if (!(t & 1u)){
            #pragma unroll
            for (int n=0;n<16;n++) a[n] = tile[((t&63u)>>1) | ((unsigned)n<<5) | ((t>>6)<<9)];
        }
        __syncthreads();
        if (t & 1u){
            #pragma unroll
            for (int i=0;i<16;i++) tile[(t>>1) | ((unsigned)i<<8)] = a[i];
        }
        __syncthreads();
        if (t & 1u){
            #pragma unroll
            for (int n=0;n<16;n++) a[n] = tile[((t&63u)>>1) | ((unsigned)n<<5) | ((t>>6)<<9)];
        }
    }
    // Trip B (R8 verbatim): i0=f6,i1=f7,i2=f8,i3=f9 ; t0=f0..t5=f5, t6..8=f10..12
    #pragma unroll
    for (int j=0;j<16;j++){ if (j&1) continue; ry_pair(a[j],a[j|1],cB[6],sB[6]); }
    #pragma unroll
    for (int j=0;j<16;j++){ if (j&2) continue; ry_pair(a[j],a[j|2],cB[7],sB[7]); }
    #pragma unroll
    for (int j=0;j<16;j++){ if (j&4) continue; ry_pair(a[j],a[j|4],cB[8],sB[8]); }
    #pragma unroll
    for (int j=0;j<16;j++){ if (j&4) continue; if ((j>>3)&1){ float2 tm=a[j]; a[j]=a[j|4]; a[j|4]=tm; } } // (9->8)
    #pragma unroll
    for (int j=0;j<16;j++){ if (j&2) continue; if ((j>>2)&1){ float2 tm=a[j]; a[j]=a[j|2]; a[j|2]=tm; } } // (8->7)
    #pragma unroll
    for (int j=0;j<16;j++){ if (j&1) continue; if ((j>>1)&1){ float2 tm=a[j]; a[j]=a[j|1]; a[j|1]=tm; } } // (7->6)
    #pragma unroll
    for (int i=0;i<16;i++) a[i] = cmul(a[i], E2B[i&7]);      // Rz2(f6..8)
    #pragma unroll
    for (int j=0;j<16;j++){ if (j&2) continue; ry_pair(a[j],a[j|2],cC[7],sC[7]); }
    #pragma unroll
    for (int j=0;j<16;j++){ if (j&4) continue; ry_pair(a[j],a[j|4],cC[8],sC[8]); }
    #pragma unroll
    for (int j=0;j<16;j++){ if (j&8) continue; ry_pair(a[j],a[j|8],cC[9],sC[9]); }

    // ---- transpose B -> C: thread-split f0; fold2 on both sides.
    //   B-coords: ((t&63)>>1)[f1..5] | i<<5[f6..9] | (t>>6)<<9[f10..12]
    //   C-coords: ((t>>1)&3)[f1,f2] | n<<2[f3..6] | (t>>3)<<6[f7..12]
    {
        __syncthreads();
        if (!(t & 1u)){
            #pragma unroll
            for (int i=0;i<16;i++) tile[fold2(((t&63u)>>1) | ((unsigned)i<<5) | ((t>>6)<<9))] = a[i];
        }
        __syncthreads();
        if (!(t & 1u)){
            #pragma unroll
            for (int n=0;n<16;n++) a[n] = tile[fold2(((t>>1)&3u) | ((unsigned)n<<2) | ((t>>3)<<6))];
        }
        __syncthreads();
        if (t & 1u){
            #pragma unroll
            for (int i=0;i<16;i++) tile[fold2(((t&63u)>>1) | ((unsigned)i<<5) | ((t>>6)<<9))] = a[i];
        }
        __syncthreads();
        if (t & 1u){
            #pragma unroll
            for (int n=0;n<16;n++) a[n] = tile[fold2(((t>>1)&3u) | ((unsigned)n<<2) | ((t>>3)<<6))];
        }
    }
    // Trip C (R8 verbatim): i0=f3,i1=f4,i2=f5,i3=f6 ; t0..2=f0..2, t3..8=f7..12
    #pragma unroll
    for (int j=0;j<16;j++){ if (j&1) continue; ry_pair(a[j],a[j|1],cB[3],sB[3]); }
    #pragma unroll
    for (int j=0;j<16;j++){ if (j&2) continue; ry_pair(a[j],a[j|2],cB[4],sB[4]); }
    #pragma unroll
    for (int j=0;j<16;j++){ if (j&4) continue; ry_pair(a[j],a[j|4],cB[5],sB[5]); }
    #pragma unroll
    for (int j=0;j<16;j++){ if (j&4) continue; if ((j>>3)&1){ float2 tm=a[j]; a[j]=a[j|4]; a[j|4]=tm; } } // (6->5)
    #pragma unroll
    for (int j=0;j<16;j++){ if (j&2) continue; if ((j>>2)&1){ float2 tm=a[j]; a[j]=a[j|2]; a[j|2]=tm; } } // (5->4)
    #pragma unroll
    for (int j=0;j<16;j++){ if (j&1) continue; if ((j>>1)&1){ float2 tm=a[j]; a[j]=a[j|1]; a[j|1]=tm; } } // (4->3)
    #pragma unroll
    for (int i=0;i<16;i++) a[i] = cmul(a[i], E2C[i&7]);      // Rz2(f3..5)
    #pragma unroll
    for (int j=0;j<16;j++){ if (j&2) continue; ry_pair(a[j],a[j|2],cC[4],sC[4]); }
    #pragma unroll
    for (int j=0;j<16;j++){ if (j&4) continue; ry_pair(a[j],a[j|4],cC[5],sC[5]); }
    #pragma unroll
    for (int j=0;j<16;j++){ if (j&8) continue; ry_pair(a[j],a[j|8],cC[6],sC[6]); }

    // ---- transpose C -> D: thread-split f7 (t bit3); fold3 both sides.
    //   C-coords: (t&7)[f0..2] | i<<3[f3..6] | (t>>4)<<7[f8..12]
    //   D-coords: n[f0..3] | (t&7)<<4[f4..6] | (t>>4)<<7[f8..12]
    {
        __syncthreads();
        if (!((t>>3) & 1u)){
            #pragma unroll
            for (int i=0;i<16;i++) tile[fold3((t&7u) | ((unsigned)i<<3) | ((t>>4)<<7))] = a[i];
        }
        __syncthreads();
        if (!((t>>3) & 1u)){
            #pragma unroll
            for (int n=0;n<16;n++) a[n] = tile[fold3((unsigned)n | ((t&7u)<<4) | ((t>>4)<<7))];
        }
        __syncthreads();
        if ((t>>3) & 1u){
            #pragma unroll
            for (int i=0;i<16;i++) tile[fold3((t&7u) | ((unsigned)i<<3) | ((t>>4)<<7))] = a[i];
        }
        __syncthreads();
        if ((t>>3) & 1u){
            #pragma unroll
            for (int n=0;n<16;n++) a[n] = tile[fold3((unsigned)n | ((t&7u)<<4) | ((t>>4)<<7))];
        }
    }
    // Trip D (R8 verbatim): i0=f0,i1=f1,i2=f2,i3=f3 ; t0..8=f4..12
    #pragma unroll
    for (int j=0;j<16;j++){ if (j&1) continue; ry_pair(a[j],a[j|1],cB[0],sB[0]); }
    #pragma unroll
    for (int j=0;j<16;j++){ if (j&2) continue; ry_pair(a[j],a[j|2],cB[1],sB[1]); }
    #pragma unroll
    for (int j=0;j<16;j++){ if (j&4) continue; ry_pair(a[j],a[j|4],cB[2],sB[2]); }
    #pragma unroll
    for (int j=0;j<16;j++){ if (j&4) continue; if ((j>>3)&1){ float2 tm=a[j]; a[j]=a[j|4]; a[j|4]=tm; } } // (3->2)
    #pragma unroll
    for (int j=0;j<16;j++){ if (j&2) continue; if ((j>>2)&1){ float2 tm=a[j]; a[j]=a[j|2]; a[j|2]=tm; } } // (2->1)
    #pragma unroll
    for (int j=0;j<16;j++){ if (j&1) continue; if ((j>>1)&1){ float2 tm=a[j]; a[j]=a[j|1]; a[j|1]=tm; } } // (1->0)
    #pragma unroll
    for (int i=0;i<16;i++) a[i] = cmul(a[i], E2D[i&7]);      // Rz2(f0..2,f13,f14)
    #pragma unroll
    for (int j=0;j<16;j++){ if (j&2) continue; ry_pair(a[j],a[j|2],cC[1],sC[1]); }
    #pragma unroll
    for (int j=0;j<16;j++){ if (j&4) continue; ry_pair(a[j],a[j|4],cC[2],sC[2]); }
    #pragma unroll
    for (int j=0;j<16;j++){ if (j&8) continue; ry_pair(a[j],a[j|8],cC[3],sC[3]); }

    // ---- transpose D -> store layout: reg-split on f0 (R10-verified addresses),
    //   nb[8] + phase-1 reads straight into odd a-slots.
    {
        float2 nb[8];
        __syncthreads();
        #pragma unroll
        for (int i=0;i<16;i+=2) tile[swz((unsigned)(i>>1) | (t<<3))] = a[i];      // f0=0
        __syncthreads();
        #pragma unroll
        for (int k=0;k<8;k++) nb[k] = tile[swz((unsigned)(k&1) | (t<<1) | ((unsigned)(k>>1)<<10))];
        __syncthreads();
        #pragma unroll
        for (int i=1;i<16;i+=2) tile[swz((unsigned)(i>>1) | (t<<3))] = a[i];      // f0=1
        __syncthreads();
        #pragma unroll
        for (int k=0;k<8;k++) a[(k<<1)|1] = tile[swz((unsigned)(k&1) | (t<<1) | ((unsigned)(k>>1)<<10))];
        #pragma unroll
        for (int k=0;k<8;k++) a[k<<1] = nb[k];
    }
    // ---- coalesced store (R10-verified): f = (t<<2)|(u<<11); n: f0,f1,f11,f12
    float2* sp = st + ((size_t)b<<16);
    #pragma unroll
    for (int u=0;u<4;u++){
        float4* d4 = (float4*)(sp + ((t<<2) | ((unsigned)u<<11) | (outer<<13)));
        d4[0]=make_float4(a[4*u+0].x,a[4*u+0].y,a[4*u+1].x,a[4*u+1].y);
        d4[1]=make_float4(a[4*u+2].x,a[4*u+2].y,a[4*u+3].x,a[4*u+3].y);
    }
}

// ---------------- P2 k_fin (B-type, outer = f10..12, READ, no LDS tile) — verbatim
__global__ __launch_bounds__(256) void k_fin(const float* __restrict__ xg,
                                             const float* __restrict__ pg,
                                             const float2* __restrict__ st,
                                             float* __restrict__ outg)
{
    __shared__ float cN[16], sN[16];
    __shared__ float snp, csp;
    __shared__ float red[4][3];
    const int tid = threadIdx.x;
    const int b = blockIdx.x >> 3;
    const unsigned outer = blockIdx.x & 7u;        // f bits 10..12
    if (tid < 16){
        int j=tid, q=15-j;
        float th = 0.5f*(xg[b*16+q]*PI_F + pg[64 + q]);      // Ry3
        float s,c; __sincosf(th,&s,&c);
        cN[j]=c; sN[j]=s;
    }
    if (tid==16){ float phi = 0.5f*pg[48 + 0]; float s,c; __sincosf(phi,&s,&c); snp=s; csp=c; }
    __syncthreads();
    const unsigned t = tid;
    const float2* sp = st + ((size_t)b<<16);
    float2 a[32];
    #pragma unroll
    for (int u=0;u<8;u++){
        unsigned fb = (t<<2) | (outer<<10) | ((unsigned)u<<13);
        const float4* s4 = (const float4*)(sp + fb);
        float4 v0=s4[0], v1=s4[1];
        a[4*u+0]=make_float2(v0.x,v0.y); a[4*u+1]=make_float2(v0.z,v0.w);
        a[4*u+2]=make_float2(v1.x,v1.y); a[4*u+3]=make_float2(v1.z,v1.w);
    }
    // CN2(0->15): ctrl f0 = i0, tgt f15 = i4
    #pragma unroll
    for (int j=0;j<32;j++){ if (j&16) continue; if (j&1){ float2 tm=a[j]; a[j]=a[j|16]; a[j|16]=tm; } }
    // Rz2(f15)
    #pragma unroll
    for (int j=0;j<32;j++){
        float sn = ((j>>4)&1)? snp : -snp;
        float2 v=a[j];
        a[j]=make_float2(v.x*csp - v.y*sn, v.x*sn + v.y*csp);
    }
    #pragma unroll
    for (int j=0;j<32;j++){ if (j&1)  continue; ry_pair(a[j],a[j|1] ,cN[0] ,sN[0]);  }
    #pragma unroll
    for (int j=0;j<32;j++){ if (j&4)  continue; ry_pair(a[j],a[j|4] ,cN[13],sN[13]); }
    #pragma unroll
    for (int j=0;j<32;j++){ if (j&8)  continue; ry_pair(a[j],a[j|8] ,cN[14],sN[14]); }
    #pragma unroll
    for (int j=0;j<32;j++){ if (j&16) continue; ry_pair(a[j],a[j|16],cN[15],sN[15]); }
    const int pto = (__popc(t) + __popc(outer)) & 1;   // parity(f2..f12)
    float v0=0.f, v1=0.f, v2=0.f;
    #pragma unroll
    for (int i=0;i<32;i++){
        const int i0=i&1, i1=(i>>1)&1, i2=(i>>2)&1, i3=(i>>3)&1, i4=(i>>4)&1;
        const float pr = a[i].x*a[i].x + a[i].y*a[i].y;
        v0 += (i0^i1^i2^i3^pto)? -pr : pr;   // parity(f0..f14)
        v1 += (i3^i4)?           -pr : pr;   // f14^f15
        v2 += (i2^i3^i4)?        -pr : pr;   // f13^f14^f15
    }
    #pragma unroll
    for (int off=32; off>0; off>>=1){
        v0 += __shfl_down(v0, off);
        v1 += __shfl_down(v1, off);
        v2 += __shfl_down(v2, off);
    }
    const int wv = tid>>6, ln = tid&63;
    if (ln==0){ red[wv][0]=v0; red[wv][1]=v1; red[wv][2]=v2; }
    __syncthreads();
    if (tid<3){
        float s = red[0][tid]+red[1][tid]+red[2][tid]+red[3][tid];
        atomicAdd(&outg[b*3+tid], s);
    }
}

extern "C" void kernel_launch(void* const* d_in, const int* in_sizes, int n_in,
                              void* d_out, int out_size, void* d_ws, size_t ws_size,
                              hipStream_t stream)
{
    const float* x = (const float*)d_in[0];
    const float* params = (const float*)d_in[1];
    float* out = (float*)d_out;
    float2* st = (float2*)d_ws;
    const int B = in_sizes[0] / 16;

    hipMemsetAsync(d_out, 0, (size_t)out_size*sizeof(float), stream);

    const size_t per = (size_t)65536 * sizeof(float2);   // 512 KB per batch element
    int chunk = (int)(ws_size / per);
    if (chunk > 256) chunk = 256;                        // 128 MB -> L3-resident handoff
    if (chunk < 1) chunk = 1;
    if (chunk > B) chunk = B;
    for (int b0=0; b0<B; b0+=chunk){
        const int nb = (B-b0 < chunk) ? (B-b0) : chunk;
        const float* xb = x + (size_t)b0*16;
        float* ob = out + (size_t)b0*3;
        hipLaunchKernelGGL(k_all, dim3(nb*8), dim3(512), 0, stream, xb, params, st);
        hipLaunchKernelGGL(k_fin, dim3(nb*8), dim3(256), 0, stream, xb, params, st, ob);
    }
}

// Round 14
// 173.186 us; speedup vs baseline: 1.9199x; 1.3747x over previous
//
#include <hip/hip_runtime.h>
#include <hip/hip_bf16.h>
#include <hip/hip_fp16.h>

#define PI_F 3.14159265f

// Flat index convention: state.reshape((2,)*16) => qubit q <-> flat bit j = 15-q.
// Per layer: Ry(all f), CNOT chain (15->14),(14->13),...,(1->0),(0->15), Rz(all f).
// Measurement <Z_q> q=0,1,2 -> flat bits 15,14,13.
//
// 2-pass structure, intermediate state stored as __half2 (4 B/amp, 256 KB/elem):
//   P1 k_all (outer=f13..15, 512 thr, 16 amps/thr, WRITE-only), R8-verified
//     algebra/gates/transposes (64 KB tile, launch_bounds (512,4), no spill).
//     Final D->S transpose read: (i&3) | (t<<2) | ((i>>2)<<11)  [R13 bug was
//     <<10, colliding with t bit8 -> 3/4 aliased].  Epilogue packs 4 amps ->
//     one uint4 (16 B), fully coalesced.
//   P2 k_fin (outer=f10..12, 256 thr, READ-only): loads uint4 = 4 half2 amps,
//     converts to f32, then R5-verified tail: CN2(0->15), Rz2(f15),
//     Ry3{0,13,14,15}, measurement with CN3 transported:
//     Z_f15 -> parity(f0..f14); Z_f14 -> f14^f15; Z_f13 -> f13^f14^f15.
// Single chunk of 512 elements: 512 x 256 KB = 134 MB < 256 MB L3 -> the whole
// P1->P2 handoff is Infinity-Cache-resident; 2 dispatches total.
// Half-precision error budget: unit-norm state, |a|^2 rel err ~2^-10, signed
// sum of 65536 terms -> absmax ~1e-4; threshold 3.9e-3.

__device__ __forceinline__ unsigned swz(unsigned l){ return l ^ ((l>>5)&31u); }

__device__ __forceinline__ float2 cmul(float2 a, float2 b){
    return make_float2(a.x*b.x - a.y*b.y, a.x*b.y + a.y*b.x);
}

__device__ __forceinline__ void ry_pair(float2& A0, float2& A1, float c, float s){
    float2 a0=A0, a1=A1;
    A0 = make_float2(c*a0.x - s*a1.x, c*a0.y - s*a1.y);
    A1 = make_float2(s*a0.x + c*a1.x, s*a0.y + c*a1.y);
}

// ---------------- P1: full generation + layer2(- (0->15),Rz2(f15)) + Ry3(1..12)
__global__ __launch_bounds__(512, 4) void k_all(const float* __restrict__ xg,
                                                const float* __restrict__ pg,
                                                __half2* __restrict__ st)
{
    __shared__ float2 tile[8192];
    __shared__ float cA[16], sA[16], cB[16], sB[16], cC[16], sC[16], phz1[16], phz2[16];
    __shared__ float2 K4[4], D1[16], E2A[16], E2B[8], E2C[8], E2D[8];
    const int tid = threadIdx.x;
    const int b = blockIdx.x >> 3;
    const unsigned outer = blockIdx.x & 7u;        // f13..15 (post-fold basis)

    // ---- stage 1: angle tables
    if (tid < 16){
        int j = tid, q = 15 - j;
        float th = 0.5f*(xg[b*16+q]*PI_F + pg[q]);           // Ry1
        __sincosf(th, &sA[j], &cA[j]);
    } else if (tid < 32){
        int j = tid-16, q = 15 - j;
        float th = 0.5f*(xg[b*16+q]*PI_F + pg[32+q]);        // Ry2
        __sincosf(th, &sB[j], &cB[j]);
    } else if (tid < 48){
        int j = tid-32, q = 15 - j;
        float th = 0.5f*(xg[b*16+q]*PI_F + pg[64+q]);        // Ry3
        __sincosf(th, &sC[j], &cC[j]);
    } else if (tid < 64){
        int j = tid-48, q = 15 - j;
        phz1[j] = 0.5f*pg[16+q];                              // Rz1
    } else if (tid < 80){
        int j = tid-64, q = 15 - j;
        phz2[j] = 0.5f*pg[48+q];                              // Rz2
    }
    __syncthreads();
    // ---- stage 2: block-uniform tables (R6/R8-verified)
    if (tid < 4){
        const unsigned o13=outer&1u, o14=(outer>>1)&1u, o15=(outer>>2)&1u;
        const unsigned h13=o13^o14, h14=o14^o15, h15=o15;
        const int f0b=(tid>>1)&1, f12b=tid&1;
        float Kr=0.f, Ki=0.f;
        #pragma unroll
        for (int g=0; g<8; ++g){
            const unsigned g13=g&1u, g14=(g>>1)&1u, g15=(g>>2)&1u;
            float w;
            w  = (h13==g13)? cB[13] : (h13? sB[13] : -sB[13]);
            w *= (h14==g14)? cB[14] : (h14? sB[14] : -sB[14]);
            w *= (h15==g15)? cB[15] : (h15? sB[15] : -sB[15]);
            w *= (f12b^(int)g13)?          sA[12]:cA[12];
            w *= ((int)(g13^g14))?         sA[13]:cA[13];
            w *= ((int)g14^f0b^(int)g15)?  sA[14]:cA[14];
            w *= (f0b^(int)g15)?           sA[15]:cA[15];
            float phg = (g13? phz1[13]:-phz1[13]) + (g14? phz1[14]:-phz1[14])
                      + (g15? phz1[15]:-phz1[15]);
            float sn,cs; __sincosf(phg,&sn,&cs);
            Kr += w*cs; Ki += w*sn;
        }
        K4[tid] = make_float2(Kr,Ki);
    } else if (tid>=16 && tid<32){
        const int ii = tid-16;  // Rz1 deltas over f9..12
        float d=0.f;
        #pragma unroll
        for (int j=0;j<4;j++) d += ((ii>>j)&1)? phz1[9+j]:-phz1[9+j];
        float sn,cs; __sincosf(d,&sn,&cs); D1[ii]=make_float2(cs,sn);
    } else if (tid>=32 && tid<48){
        const int ii = tid-32;  // Rz2 over f9..12
        float d=0.f;
        #pragma unroll
        for (int j=0;j<4;j++) d += ((ii>>j)&1)? phz2[9+j]:-phz2[9+j];
        float sn,cs; __sincosf(d,&sn,&cs); E2A[ii]=make_float2(cs,sn);
    } else if (tid>=48 && tid<56){
        const int ii = tid-48;  // Rz2 over f6..8
        float d=0.f;
        #pragma unroll
        for (int j=0;j<3;j++) d += ((ii>>j)&1)? phz2[6+j]:-phz2[6+j];
        float sn,cs; __sincosf(d,&sn,&cs); E2B[ii]=make_float2(cs,sn);
    } else if (tid>=56 && tid<64){
        const int ii = tid-56;  // Rz2 over f3..5
        float d=0.f;
        #pragma unroll
        for (int j=0;j<3;j++) d += ((ii>>j)&1)? phz2[3+j]:-phz2[3+j];
        float sn,cs; __sincosf(d,&sn,&cs); E2C[ii]=make_float2(cs,sn);
    } else if (tid>=64 && tid<72){
        const int ii = tid-64;  // Rz2 over f0..2 + uniform f13,f14
        float d=0.f;
        #pragma unroll
        for (int j=0;j<3;j++) d += ((ii>>j)&1)? phz2[j]:-phz2[j];
        d += (outer&1u)?      phz2[13]:-phz2[13];
        d += ((outer>>1)&1u)? phz2[14]:-phz2[14];
        float sn,cs; __sincosf(d,&sn,&cs); E2D[ii]=make_float2(cs,sn);
    }
    __syncthreads();

    const unsigned t = tid;                 // trip A: t = f0..8 (9 bits)
    float2 a[16];
    // ---- Trip A generation: i = f9..12  (R8-verified)
    {
        float base_t = 1.0f;
        #pragma unroll
        for (int j=0;j<8;j++){
            int v = (int)(((t>>j)^(t>>(j+1)))&1u);           // b_pre[j]=f_j^f_{j+1}
            base_t *= v? sA[j]:cA[j];
        }
        float pht = 0.f;
        #pragma unroll
        for (int j=0;j<9;j++) pht += ((t>>j)&1u)? phz1[j]:-phz1[j];
        float Ety,Etx; __sincosf(pht,&Ety,&Etx);
        const float2 Et = make_float2(Etx,Ety);
        const unsigned t0 = t&1u;
        const float2 EK0 = cmul(Et, K4[t0<<1]);
        const float2 EK1 = cmul(Et, K4[(t0<<1)|1u]);
        const int t8 = (int)((t>>8)&1u);
        #pragma unroll
        for (int i=0;i<16;i++){
            const int i0=i&1, i1=(i>>1)&1, i2=(i>>2)&1, i3=(i>>3)&1;
            float pr = base_t;
            pr *= (t8^i0)? sA[8] :cA[8];                     // b_pre[8]=f8^f9
            pr *= (i0^i1)? sA[9] :cA[9];
            pr *= (i1^i2)? sA[10]:cA[10];
            pr *= (i2^i3)? sA[11]:cA[11];
            float2 w = cmul(D1[i], i3? EK1:EK0);
            a[i] = make_float2(pr*w.x, pr*w.y);
        }
    }
    // Trip A gates: i0=f9,i1=f10,i2=f11,i3=f12
    #pragma unroll
    for (int j=0;j<16;j++){ if (j&1)  continue; ry_pair(a[j],a[j|1] ,cB[9] ,sB[9]);  }
    #pragma unroll
    for (int j=0;j<16;j++){ if (j&2)  continue; ry_pair(a[j],a[j|2] ,cB[10],sB[10]); }
    #pragma unroll
    for (int j=0;j<16;j++){ if (j&4)  continue; ry_pair(a[j],a[j|4] ,cB[11],sB[11]); }
    #pragma unroll
    for (int j=0;j<16;j++){ if (j&8)  continue; ry_pair(a[j],a[j|8] ,cB[12],sB[12]); }
    if (outer & 1u){  // CN2(13->12): ctrl f13=o13 (uniform), tgt i3
        #pragma unroll
        for (int j=0;j<16;j++){ if (j&8) continue; float2 tm=a[j]; a[j]=a[j|8]; a[j|8]=tm; }
    }
    #pragma unroll
    for (int j=0;j<16;j++){ if (j&4) continue; if ((j>>3)&1){ float2 tm=a[j]; a[j]=a[j|4]; a[j|4]=tm; } } // (12->11)
    #pragma unroll
    for (int j=0;j<16;j++){ if (j&2) continue; if ((j>>2)&1){ float2 tm=a[j]; a[j]=a[j|2]; a[j|2]=tm; } } // (11->10)
    #pragma unroll
    for (int j=0;j<16;j++){ if (j&1) continue; if ((j>>1)&1){ float2 tm=a[j]; a[j]=a[j|1]; a[j|1]=tm; } } // (10->9)
    #pragma unroll
    for (int i=0;i<16;i++) a[i] = cmul(a[i], E2A[i]);        // Rz2(f9..12)
    #pragma unroll
    for (int j=0;j<16;j++){ if (j&2)  continue; ry_pair(a[j],a[j|2] ,cC[10],sC[10]); }
    #pragma unroll
    for (int j=0;j<16;j++){ if (j&4)  continue; ry_pair(a[j],a[j|4] ,cC[11],sC[11]); }
    #pragma unroll
    for (int j=0;j<16;j++){ if (j&8)  continue; ry_pair(a[j],a[j|8] ,cC[12],sC[12]); }
    // ---- transpose A -> B
    #pragma unroll
    for (int i=0;i<16;i++) tile[swz(t | ((unsigned)i<<9))] = a[i];
    __syncthreads();
    #pragma unroll
    for (int i=0;i<16;i++) a[i] = tile[swz((t&63u) | ((unsigned)i<<6) | ((t>>6)<<10))];
    // Trip B: i0=f6,i1=f7,i2=f8,i3=f9 ; t&63=f0..5, t>>6=f10..12
    #pragma unroll
    for (int j=0;j<16;j++){ if (j&1) continue; ry_pair(a[j],a[j|1],cB[6],sB[6]); }
    #pragma unroll
    for (int j=0;j<16;j++){ if (j&2) continue; ry_pair(a[j],a[j|2],cB[7],sB[7]); }
    #pragma unroll
    for (int j=0;j<16;j++){ if (j&4) continue; ry_pair(a[j],a[j|4],cB[8],sB[8]); }
    #pragma unroll
    for (int j=0;j<16;j++){ if (j&4) continue; if ((j>>3)&1){ float2 tm=a[j]; a[j]=a[j|4]; a[j|4]=tm; } } // (9->8)
    #pragma unroll
    for (int j=0;j<16;j++){ if (j&2) continue; if ((j>>2)&1){ float2 tm=a[j]; a[j]=a[j|2]; a[j|2]=tm; } } // (8->7)
    #pragma unroll
    for (int j=0;j<16;j++){ if (j&1) continue; if ((j>>1)&1){ float2 tm=a[j]; a[j]=a[j|1]; a[j|1]=tm; } } // (7->6)
    #pragma unroll
    for (int i=0;i<16;i++) a[i] = cmul(a[i], E2B[i&7]);      // Rz2(f6..8)
    #pragma unroll
    for (int j=0;j<16;j++){ if (j&2) continue; ry_pair(a[j],a[j|2],cC[7],sC[7]); }
    #pragma unroll
    for (int j=0;j<16;j++){ if (j&4) continue; ry_pair(a[j],a[j|4],cC[8],sC[8]); }
    #pragma unroll
    for (int j=0;j<16;j++){ if (j&8) continue; ry_pair(a[j],a[j|8],cC[9],sC[9]); }
    // ---- transpose B -> C
    #pragma unroll
    for (int i=0;i<16;i++) tile[swz((t&63u) | ((unsigned)i<<6) | ((t>>6)<<10))] = a[i];
    __syncthreads();
    #pragma unroll
    for (int i=0;i<16;i++) a[i] = tile[swz((t&7u) | ((unsigned)i<<3) | ((t>>3)<<7))];
    // Trip C: i0=f3,i1=f4,i2=f5,i3=f6 ; t&7=f0..2, t>>3=f7..12
    #pragma unroll
    for (int j=0;j<16;j++){ if (j&1) continue; ry_pair(a[j],a[j|1],cB[3],sB[3]); }
    #pragma unroll
    for (int j=0;j<16;j++){ if (j&2) continue; ry_pair(a[j],a[j|2],cB[4],sB[4]); }
    #pragma unroll
    for (int j=0;j<16;j++){ if (j&4) continue; ry_pair(a[j],a[j|4],cB[5],sB[5]); }
    #pragma unroll
    for (int j=0;j<16;j++){ if (j&4) continue; if ((j>>3)&1){ float2 tm=a[j]; a[j]=a[j|4]; a[j|4]=tm; } } // (6->5)
    #pragma unroll
    for (int j=0;j<16;j++){ if (j&2) continue; if ((j>>2)&1){ float2 tm=a[j]; a[j]=a[j|2]; a[j|2]=tm; } } // (5->4)
    #pragma unroll
    for (int j=0;j<16;j++){ if (j&1) continue; if ((j>>1)&1){ float2 tm=a[j]; a[j]=a[j|1]; a[j|1]=tm; } } // (4->3)
    #pragma unroll
    for (int i=0;i<16;i++) a[i] = cmul(a[i], E2C[i&7]);      // Rz2(f3..5)
    #pragma unroll
    for (int j=0;j<16;j++){ if (j&2) continue; ry_pair(a[j],a[j|2],cC[4],sC[4]); }
    #pragma unroll
    for (int j=0;j<16;j++){ if (j&4) continue; ry_pair(a[j],a[j|4],cC[5],sC[5]); }
    #pragma unroll
    for (int j=0;j<16;j++){ if (j&8) continue; ry_pair(a[j],a[j|8],cC[6],sC[6]); }
    // ---- transpose C -> D
    #pragma unroll
    for (int i=0;i<16;i++) tile[swz((t&7u) | ((unsigned)i<<3) | ((t>>3)<<7))] = a[i];
    __syncthreads();
    #pragma unroll
    for (int i=0;i<16;i++) a[i] = tile[swz((unsigned)i | (t<<4))];
    // Trip D: i0=f0,i1=f1,i2=f2,i3=f3 ; t=f4..12
    #pragma unroll
    for (int j=0;j<16;j++){ if (j&1) continue; ry_pair(a[j],a[j|1],cB[0],sB[0]); }
    #pragma unroll
    for (int j=0;j<16;j++){ if (j&2) continue; ry_pair(a[j],a[j|2],cB[1],sB[1]); }
    #pragma unroll
    for (int j=0;j<16;j++){ if (j&4) continue; ry_pair(a[j],a[j|4],cB[2],sB[2]); }
    #pragma unroll
    for (int j=0;j<16;j++){ if (j&4) continue; if ((j>>3)&1){ float2 tm=a[j]; a[j]=a[j|4]; a[j|4]=tm; } } // (3->2)
    #pragma unroll
    for (int j=0;j<16;j++){ if (j&2) continue; if ((j>>2)&1){ float2 tm=a[j]; a[j]=a[j|2]; a[j|2]=tm; } } // (2->1)
    #pragma unroll
    for (int j=0;j<16;j++){ if (j&1) continue; if ((j>>1)&1){ float2 tm=a[j]; a[j]=a[j|1]; a[j|1]=tm; } } // (1->0)
    #pragma unroll
    for (int i=0;i<16;i++) a[i] = cmul(a[i], E2D[i&7]);      // Rz2(f0..2,f13,f14)
    #pragma unroll
    for (int j=0;j<16;j++){ if (j&2) continue; ry_pair(a[j],a[j|2],cC[1],sC[1]); }
    #pragma unroll
    for (int j=0;j<16;j++){ if (j&4) continue; ry_pair(a[j],a[j|4],cC[2],sC[2]); }
    #pragma unroll
    for (int j=0;j<16;j++){ if (j&8) continue; ry_pair(a[j],a[j|8],cC[3],sC[3]); }
    // ---- transpose D -> store layout.  Read: (i&3)|(t<<2)|((i>>2)<<11)
    //      (t is 9 bits -> occupies bits 2..10; u goes in bits 11..12.
    //       R13's <<10 collided with t bit8 -> aliasing; fixed.)
    __syncthreads();
    #pragma unroll
    for (int i=0;i<16;i++) tile[swz((unsigned)i | (t<<4))] = a[i];
    __syncthreads();
    #pragma unroll
    for (int i=0;i<16;i++) a[i] = tile[swz((unsigned)(i&3) | (t<<2) | ((unsigned)(i>>2)<<11))];
    // half2-pack + coalesced store: f = (t<<2) | (u<<11) | (outer<<13); 4 amps = 16B
    __half2* hp = st + ((size_t)b<<16);
    #pragma unroll
    for (int u=0;u<4;u++){
        __half2 hv[4];
        hv[0] = __float22half2_rn(a[4*u+0]);
        hv[1] = __float22half2_rn(a[4*u+1]);
        hv[2] = __float22half2_rn(a[4*u+2]);
        hv[3] = __float22half2_rn(a[4*u+3]);
        *reinterpret_cast<uint4*>(hp + ((t<<2) | ((unsigned)u<<11) | (outer<<13))) =
            *reinterpret_cast<uint4*>(hv);
    }
}

// ---------------- P2 k_fin (B-type, outer = f10..12, READ, no LDS tile)
__global__ __launch_bounds__(256) void k_fin(const float* __restrict__ xg,
                                             const float* __restrict__ pg,
                                             const __half2* __restrict__ st,
                                             float* __restrict__ outg)
{
    __shared__ float cN[16], sN[16];
    __shared__ float snp, csp;
    __shared__ float red[4][3];
    const int tid = threadIdx.x;
    const int b = blockIdx.x >> 3;
    const unsigned outer = blockIdx.x & 7u;        // f bits 10..12
    if (tid < 16){
        int j=tid, q=15-j;
        float th = 0.5f*(xg[b*16+q]*PI_F + pg[64 + q]);      // Ry3
        float s,c; __sincosf(th,&s,&c);
        cN[j]=c; sN[j]=s;
    }
    if (tid==16){ float phi = 0.5f*pg[48 + 0]; float s,c; __sincosf(phi,&s,&c); snp=s; csp=c; }
    __syncthreads();
    const unsigned t = tid;
    const __half2* sp = st + ((size_t)b<<16);
    float2 a[32];
    #pragma unroll
    for (int u=0;u<8;u++){
        unsigned fb = (t<<2) | (outer<<10) | ((unsigned)u<<13);
        uint4 raw = *reinterpret_cast<const uint4*>(sp + fb);
        const __half2* hv = reinterpret_cast<const __half2*>(&raw);
        a[4*u+0] = __half22float2(hv[0]);
        a[4*u+1] = __half22float2(hv[1]);
        a[4*u+2] = __half22float2(hv[2]);
        a[4*u+3] = __half22float2(hv[3]);
    }
    // CN2(0->15): ctrl f0 = i0, tgt f15 = i4
    #pragma unroll
    for (int j=0;j<32;j++){ if (j&16) continue; if (j&1){ float2 tm=a[j]; a[j]=a[j|16]; a[j|16]=tm; } }
    // Rz2(f15)
    #pragma unroll
    for (int j=0;j<32;j++){
        float sn = ((j>>4)&1)? snp : -snp;
        float2 v=a[j];
        a[j]=make_float2(v.x*csp - v.y*sn, v.x*sn + v.y*csp);
    }
    #pragma unroll
    for (int j=0;j<32;j++){ if (j&1)  continue; ry_pair(a[j],a[j|1] ,cN[0] ,sN[0]);  }
    #pragma unroll
    for (int j=0;j<32;j++){ if (j&4)  continue; ry_pair(a[j],a[j|4] ,cN[13],sN[13]); }
    #pragma unroll
    for (int j=0;j<32;j++){ if (j&8)  continue; ry_pair(a[j],a[j|8] ,cN[14],sN[14]); }
    #pragma unroll
    for (int j=0;j<32;j++){ if (j&16) continue; ry_pair(a[j],a[j|16],cN[15],sN[15]); }
    const int pto = (__popc(t) + __popc(outer)) & 1;   // parity(f2..f12)
    float v0=0.f, v1=0.f, v2=0.f;
    #pragma unroll
    for (int i=0;i<32;i++){
        const int i0=i&1, i1=(i>>1)&1, i2=(i>>2)&1, i3=(i>>3)&1, i4=(i>>4)&1;
        const float pr = a[i].x*a[i].x + a[i].y*a[i].y;
        v0 += (i0^i1^i2^i3^pto)? -pr : pr;   // parity(f0..f14)
        v1 += (i3^i4)?           -pr : pr;   // f14^f15
        v2 += (i2^i3^i4)?        -pr : pr;   // f13^f14^f15
    }
    #pragma unroll
    for (int off=32; off>0; off>>=1){
        v0 += __shfl_down(v0, off);
        v1 += __shfl_down(v1, off);
        v2 += __shfl_down(v2, off);
    }
    const int wv = tid>>6, ln = tid&63;
    if (ln==0){ red[wv][0]=v0; red[wv][1]=v1; red[wv][2]=v2; }
    __syncthreads();
    if (tid<3){
        float s = red[0][tid]+red[1][tid]+red[2][tid]+red[3][tid];
        atomicAdd(&outg[b*3+tid], s);
    }
}

extern "C" void kernel_launch(void* const* d_in, const int* in_sizes, int n_in,
                              void* d_out, int out_size, void* d_ws, size_t ws_size,
                              hipStream_t stream)
{
    const float* x = (const float*)d_in[0];
    const float* params = (const float*)d_in[1];
    float* out = (float*)d_out;
    __half2* st = (__half2*)d_ws;
    const int B = in_sizes[0] / 16;

    hipMemsetAsync(d_out, 0, (size_t)out_size*sizeof(float), stream);

    const size_t per = (size_t)65536 * sizeof(__half2);  // 256 KB per batch element
    int chunk = (int)(ws_size / per);
    if (chunk > 512) chunk = 512;                        // 512 elem = 134 MB < L3
    if (chunk < 1) chunk = 1;
    if (chunk > B) chunk = B;
    for (int b0=0; b0<B; b0+=chunk){
        const int nb = (B-b0 < chunk) ? (B-b0) : chunk;
        const float* xb = x + (size_t)b0*16;
        float* ob = out + (size_t)b0*3;
        hipLaunchKernelGGL(k_all, dim3(nb*8), dim3(512), 0, stream, xb, params, st);
        hipLaunchKernelGGL(k_fin, dim3(nb*8), dim3(256), 0, stream, xb, params, st, ob);
    }
}

// Round 15
// 170.882 us; speedup vs baseline: 1.9458x; 1.0135x over previous
//
#include <hip/hip_runtime.h>
#include <hip/hip_bf16.h>
#include <hip/hip_fp16.h>

#define PI_F 3.14159265f

// Flat index convention: state.reshape((2,)*16) => qubit q <-> flat bit j = 15-q.
// Per layer: Ry(all f), CNOT chain (15->14),(14->13),...,(1->0),(0->15), Rz(all f).
// Measurement <Z_q> q=0,1,2 -> flat bits 15,14,13.
//
// 2-pass structure, intermediate state as __half2 (4 B/amp, 256 KB/elem):
//   P1 k_all (outer=f13..15, 512 thr, 16 amps/thr, WRITE-only), R8/R14-verified
//     algebra/gates/transposes.  NEW vs R14: the LDS tile is ALSO __half2
//     (32 KB vs 64 KB) -> LDS block ~34 KB -> 4 blocks/CU -> 32-waves/CU cap
//     (R14: 41% occupancy at a 50% cap, VALU-bound with 30% barrier stalls).
//     Same barrier count/schedule as R14; only pack/unpack cvt added.
//     Final D->S trip reads half2 directly and stores (no f32 repack).
//   P2 k_fin (outer=f10..12, 256 thr, READ-only, R14-verbatim).
// Single chunk of 512 elements: 134 MB < 256 MB L3 -> handoff L3-resident.
// Precision: 4 fp16 quantization events (R14 measured 2.4e-4 with 1) ->
// absmax ~0.5-1e-3, threshold 3.9e-3.

__device__ __forceinline__ unsigned swz(unsigned l){ return l ^ ((l>>5)&31u); }

__device__ __forceinline__ float2 cmul(float2 a, float2 b){
    return make_float2(a.x*b.x - a.y*b.y, a.x*b.y + a.y*b.x);
}

__device__ __forceinline__ void ry_pair(float2& A0, float2& A1, float c, float s){
    float2 a0=A0, a1=A1;
    A0 = make_float2(c*a0.x - s*a1.x, c*a0.y - s*a1.y);
    A1 = make_float2(s*a0.x + c*a1.x, s*a0.y + c*a1.y);
}

// ---------------- P1: full generation + layer2(- (0->15),Rz2(f15)) + Ry3(1..12)
__global__ __launch_bounds__(512, 4) void k_all(const float* __restrict__ xg,
                                                const float* __restrict__ pg,
                                                __half2* __restrict__ st)
{
    __shared__ __half2 tile[8192];   // 32 KB (was 64 KB f32) -> 4 blocks/CU
    __shared__ float cA[16], sA[16], cB[16], sB[16], cC[16], sC[16], phz1[16], phz2[16];
    __shared__ float2 K4[4], D1[16], E2A[16], E2B[8], E2C[8], E2D[8];
    const int tid = threadIdx.x;
    const int b = blockIdx.x >> 3;
    const unsigned outer = blockIdx.x & 7u;        // f13..15 (post-fold basis)

    // ---- stage 1: angle tables
    if (tid < 16){
        int j = tid, q = 15 - j;
        float th = 0.5f*(xg[b*16+q]*PI_F + pg[q]);           // Ry1
        __sincosf(th, &sA[j], &cA[j]);
    } else if (tid < 32){
        int j = tid-16, q = 15 - j;
        float th = 0.5f*(xg[b*16+q]*PI_F + pg[32+q]);        // Ry2
        __sincosf(th, &sB[j], &cB[j]);
    } else if (tid < 48){
        int j = tid-32, q = 15 - j;
        float th = 0.5f*(xg[b*16+q]*PI_F + pg[64+q]);        // Ry3
        __sincosf(th, &sC[j], &cC[j]);
    } else if (tid < 64){
        int j = tid-48, q = 15 - j;
        phz1[j] = 0.5f*pg[16+q];                              // Rz1
    } else if (tid < 80){
        int j = tid-64, q = 15 - j;
        phz2[j] = 0.5f*pg[48+q];                              // Rz2
    }
    __syncthreads();
    // ---- stage 2: block-uniform tables (R6/R8-verified)
    if (tid < 4){
        const unsigned o13=outer&1u, o14=(outer>>1)&1u, o15=(outer>>2)&1u;
        const unsigned h13=o13^o14, h14=o14^o15, h15=o15;
        const int f0b=(tid>>1)&1, f12b=tid&1;
        float Kr=0.f, Ki=0.f;
        #pragma unroll
        for (int g=0; g<8; ++g){
            const unsigned g13=g&1u, g14=(g>>1)&1u, g15=(g>>2)&1u;
            float w;
            w  = (h13==g13)? cB[13] : (h13? sB[13] : -sB[13]);
            w *= (h14==g14)? cB[14] : (h14? sB[14] : -sB[14]);
            w *= (h15==g15)? cB[15] : (h15? sB[15] : -sB[15]);
            w *= (f12b^(int)g13)?          sA[12]:cA[12];
            w *= ((int)(g13^g14))?         sA[13]:cA[13];
            w *= ((int)g14^f0b^(int)g15)?  sA[14]:cA[14];
            w *= (f0b^(int)g15)?           sA[15]:cA[15];
            float phg = (g13? phz1[13]:-phz1[13]) + (g14? phz1[14]:-phz1[14])
                      + (g15? phz1[15]:-phz1[15]);
            float sn,cs; __sincosf(phg,&sn,&cs);
            Kr += w*cs; Ki += w*sn;
        }
        K4[tid] = make_float2(Kr,Ki);
    } else if (tid>=16 && tid<32){
        const int ii = tid-16;  // Rz1 deltas over f9..12
        float d=0.f;
        #pragma unroll
        for (int j=0;j<4;j++) d += ((ii>>j)&1)? phz1[9+j]:-phz1[9+j];
        float sn,cs; __sincosf(d,&sn,&cs); D1[ii]=make_float2(cs,sn);
    } else if (tid>=32 && tid<48){
        const int ii = tid-32;  // Rz2 over f9..12
        float d=0.f;
        #pragma unroll
        for (int j=0;j<4;j++) d += ((ii>>j)&1)? phz2[9+j]:-phz2[9+j];
        float sn,cs; __sincosf(d,&sn,&cs); E2A[ii]=make_float2(cs,sn);
    } else if (tid>=48 && tid<56){
        const int ii = tid-48;  // Rz2 over f6..8
        float d=0.f;
        #pragma unroll
        for (int j=0;j<3;j++) d += ((ii>>j)&1)? phz2[6+j]:-phz2[6+j];
        float sn,cs; __sincosf(d,&sn,&cs); E2B[ii]=make_float2(cs,sn);
    } else if (tid>=56 && tid<64){
        const int ii = tid-56;  // Rz2 over f3..5
        float d=0.f;
        #pragma unroll
        for (int j=0;j<3;j++) d += ((ii>>j)&1)? phz2[3+j]:-phz2[3+j];
        float sn,cs; __sincosf(d,&sn,&cs); E2C[ii]=make_float2(cs,sn);
    } else if (tid>=64 && tid<72){
        const int ii = tid-64;  // Rz2 over f0..2 + uniform f13,f14
        float d=0.f;
        #pragma unroll
        for (int j=0;j<3;j++) d += ((ii>>j)&1)? phz2[j]:-phz2[j];
        d += (outer&1u)?      phz2[13]:-phz2[13];
        d += ((outer>>1)&1u)? phz2[14]:-phz2[14];
        float sn,cs; __sincosf(d,&sn,&cs); E2D[ii]=make_float2(cs,sn);
    }
    __syncthreads();

    const unsigned t = tid;                 // trip A: t = f0..8 (9 bits)
    float2 a[16];
    // ---- Trip A generation: i = f9..12  (R8-verified)
    {
        float base_t = 1.0f;
        #pragma unroll
        for (int j=0;j<8;j++){
            int v = (int)(((t>>j)^(t>>(j+1)))&1u);           // b_pre[j]=f_j^f_{j+1}
            base_t *= v? sA[j]:cA[j];
        }
        float pht = 0.f;
        #pragma unroll
        for (int j=0;j<9;j++) pht += ((t>>j)&1u)? phz1[j]:-phz1[j];
        float Ety,Etx; __sincosf(pht,&Ety,&Etx);
        const float2 Et = make_float2(Etx,Ety);
        const unsigned t0 = t&1u;
        const float2 EK0 = cmul(Et, K4[t0<<1]);
        const float2 EK1 = cmul(Et, K4[(t0<<1)|1u]);
        const int t8 = (int)((t>>8)&1u);
        #pragma unroll
        for (int i=0;i<16;i++){
            const int i0=i&1, i1=(i>>1)&1, i2=(i>>2)&1, i3=(i>>3)&1;
            float pr = base_t;
            pr *= (t8^i0)? sA[8] :cA[8];                     // b_pre[8]=f8^f9
            pr *= (i0^i1)? sA[9] :cA[9];
            pr *= (i1^i2)? sA[10]:cA[10];
            pr *= (i2^i3)? sA[11]:cA[11];
            float2 w = cmul(D1[i], i3? EK1:EK0);
            a[i] = make_float2(pr*w.x, pr*w.y);
        }
    }
    // Trip A gates: i0=f9,i1=f10,i2=f11,i3=f12
    #pragma unroll
    for (int j=0;j<16;j++){ if (j&1)  continue; ry_pair(a[j],a[j|1] ,cB[9] ,sB[9]);  }
    #pragma unroll
    for (int j=0;j<16;j++){ if (j&2)  continue; ry_pair(a[j],a[j|2] ,cB[10],sB[10]); }
    #pragma unroll
    for (int j=0;j<16;j++){ if (j&4)  continue; ry_pair(a[j],a[j|4] ,cB[11],sB[11]); }
    #pragma unroll
    for (int j=0;j<16;j++){ if (j&8)  continue; ry_pair(a[j],a[j|8] ,cB[12],sB[12]); }
    if (outer & 1u){  // CN2(13->12): ctrl f13=o13 (uniform), tgt i3
        #pragma unroll
        for (int j=0;j<16;j++){ if (j&8) continue; float2 tm=a[j]; a[j]=a[j|8]; a[j|8]=tm; }
    }
    #pragma unroll
    for (int j=0;j<16;j++){ if (j&4) continue; if ((j>>3)&1){ float2 tm=a[j]; a[j]=a[j|4]; a[j|4]=tm; } } // (12->11)
    #pragma unroll
    for (int j=0;j<16;j++){ if (j&2) continue; if ((j>>2)&1){ float2 tm=a[j]; a[j]=a[j|2]; a[j|2]=tm; } } // (11->10)
    #pragma unroll
    for (int j=0;j<16;j++){ if (j&1) continue; if ((j>>1)&1){ float2 tm=a[j]; a[j]=a[j|1]; a[j|1]=tm; } } // (10->9)
    #pragma unroll
    for (int i=0;i<16;i++) a[i] = cmul(a[i], E2A[i]);        // Rz2(f9..12)
    #pragma unroll
    for (int j=0;j<16;j++){ if (j&2)  continue; ry_pair(a[j],a[j|2] ,cC[10],sC[10]); }
    #pragma unroll
    for (int j=0;j<16;j++){ if (j&4)  continue; ry_pair(a[j],a[j|4] ,cC[11],sC[11]); }
    #pragma unroll
    for (int j=0;j<16;j++){ if (j&8)  continue; ry_pair(a[j],a[j|8] ,cC[12],sC[12]); }
    // ---- transpose A -> B (fp16 tile)
    #pragma unroll
    for (int i=0;i<16;i++) tile[swz(t | ((unsigned)i<<9))] = __float22half2_rn(a[i]);
    __syncthreads();
    #pragma unroll
    for (int i=0;i<16;i++) a[i] = __half22float2(tile[swz((t&63u) | ((unsigned)i<<6) | ((t>>6)<<10))]);
    // Trip B: i0=f6,i1=f7,i2=f8,i3=f9 ; t&63=f0..5, t>>6=f10..12
    #pragma unroll
    for (int j=0;j<16;j++){ if (j&1) continue; ry_pair(a[j],a[j|1],cB[6],sB[6]); }
    #pragma unroll
    for (int j=0;j<16;j++){ if (j&2) continue; ry_pair(a[j],a[j|2],cB[7],sB[7]); }
    #pragma unroll
    for (int j=0;j<16;j++){ if (j&4) continue; ry_pair(a[j],a[j|4],cB[8],sB[8]); }
    #pragma unroll
    for (int j=0;j<16;j++){ if (j&4) continue; if ((j>>3)&1){ float2 tm=a[j]; a[j]=a[j|4]; a[j|4]=tm; } } // (9->8)
    #pragma unroll
    for (int j=0;j<16;j++){ if (j&2) continue; if ((j>>2)&1){ float2 tm=a[j]; a[j]=a[j|2]; a[j|2]=tm; } } // (8->7)
    #pragma unroll
    for (int j=0;j<16;j++){ if (j&1) continue; if ((j>>1)&1){ float2 tm=a[j]; a[j]=a[j|1]; a[j|1]=tm; } } // (7->6)
    #pragma unroll
    for (int i=0;i<16;i++) a[i] = cmul(a[i], E2B[i&7]);      // Rz2(f6..8)
    #pragma unroll
    for (int j=0;j<16;j++){ if (j&2) continue; ry_pair(a[j],a[j|2],cC[7],sC[7]); }
    #pragma unroll
    for (int j=0;j<16;j++){ if (j&4) continue; ry_pair(a[j],a[j|4],cC[8],sC[8]); }
    #pragma unroll
    for (int j=0;j<16;j++){ if (j&8) continue; ry_pair(a[j],a[j|8],cC[9],sC[9]); }
    // ---- transpose B -> C
    #pragma unroll
    for (int i=0;i<16;i++) tile[swz((t&63u) | ((unsigned)i<<6) | ((t>>6)<<10))] = __float22half2_rn(a[i]);
    __syncthreads();
    #pragma unroll
    for (int i=0;i<16;i++) a[i] = __half22float2(tile[swz((t&7u) | ((unsigned)i<<3) | ((t>>3)<<7))]);
    // Trip C: i0=f3,i1=f4,i2=f5,i3=f6 ; t&7=f0..2, t>>3=f7..12
    #pragma unroll
    for (int j=0;j<16;j++){ if (j&1) continue; ry_pair(a[j],a[j|1],cB[3],sB[3]); }
    #pragma unroll
    for (int j=0;j<16;j++){ if (j&2) continue; ry_pair(a[j],a[j|2],cB[4],sB[4]); }
    #pragma unroll
    for (int j=0;j<16;j++){ if (j&4) continue; ry_pair(a[j],a[j|4],cB[5],sB[5]); }
    #pragma unroll
    for (int j=0;j<16;j++){ if (j&4) continue; if ((j>>3)&1){ float2 tm=a[j]; a[j]=a[j|4]; a[j|4]=tm; } } // (6->5)
    #pragma unroll
    for (int j=0;j<16;j++){ if (j&2) continue; if ((j>>2)&1){ float2 tm=a[j]; a[j]=a[j|2]; a[j|2]=tm; } } // (5->4)
    #pragma unroll
    for (int j=0;j<16;j++){ if (j&1) continue; if ((j>>1)&1){ float2 tm=a[j]; a[j]=a[j|1]; a[j|1]=tm; } } // (4->3)
    #pragma unroll
    for (int i=0;i<16;i++) a[i] = cmul(a[i], E2C[i&7]);      // Rz2(f3..5)
    #pragma unroll
    for (int j=0;j<16;j++){ if (j&2) continue; ry_pair(a[j],a[j|2],cC[4],sC[4]); }
    #pragma unroll
    for (int j=0;j<16;j++){ if (j&4) continue; ry_pair(a[j],a[j|4],cC[5],sC[5]); }
    #pragma unroll
    for (int j=0;j<16;j++){ if (j&8) continue; ry_pair(a[j],a[j|8],cC[6],sC[6]); }
    // ---- transpose C -> D
    #pragma unroll
    for (int i=0;i<16;i++) tile[swz((t&7u) | ((unsigned)i<<3) | ((t>>3)<<7))] = __float22half2_rn(a[i]);
    __syncthreads();
    #pragma unroll
    for (int i=0;i<16;i++) a[i] = __half22float2(tile[swz((unsigned)i | (t<<4))]);
    // Trip D: i0=f0,i1=f1,i2=f2,i3=f3 ; t=f4..12
    #pragma unroll
    for (int j=0;j<16;j++){ if (j&1) continue; ry_pair(a[j],a[j|1],cB[0],sB[0]); }
    #pragma unroll
    for (int j=0;j<16;j++){ if (j&2) continue; ry_pair(a[j],a[j|2],cB[1],sB[1]); }
    #pragma unroll
    for (int j=0;j<16;j++){ if (j&4) continue; ry_pair(a[j],a[j|4],cB[2],sB[2]); }
    #pragma unroll
    for (int j=0;j<16;j++){ if (j&4) continue; if ((j>>3)&1){ float2 tm=a[j]; a[j]=a[j|4]; a[j|4]=tm; } } // (3->2)
    #pragma unroll
    for (int j=0;j<16;j++){ if (j&2) continue; if ((j>>2)&1){ float2 tm=a[j]; a[j]=a[j|2]; a[j|2]=tm; } } // (2->1)
    #pragma unroll
    for (int j=0;j<16;j++){ if (j&1) continue; if ((j>>1)&1){ float2 tm=a[j]; a[j]=a[j|1]; a[j|1]=tm; } } // (1->0)
    #pragma unroll
    for (int i=0;i<16;i++) a[i] = cmul(a[i], E2D[i&7]);      // Rz2(f0..2,f13,f14)
    #pragma unroll
    for (int j=0;j<16;j++){ if (j&2) continue; ry_pair(a[j],a[j|2],cC[1],sC[1]); }
    #pragma unroll
    for (int j=0;j<16;j++){ if (j&4) continue; ry_pair(a[j],a[j|4],cC[2],sC[2]); }
    #pragma unroll
    for (int j=0;j<16;j++){ if (j&8) continue; ry_pair(a[j],a[j|8],cC[3],sC[3]); }
    // ---- transpose D -> store layout (read: (i&3)|(t<<2)|((i>>2)<<11), R14-verified).
    //      Tile already fp16 -> read half2 and store directly, no f32 repack.
    __syncthreads();
    #pragma unroll
    for (int i=0;i<16;i++) tile[swz((unsigned)i | (t<<4))] = __float22half2_rn(a[i]);
    __syncthreads();
    __half2* hp = st + ((size_t)b<<16);
    #pragma unroll
    for (int u=0;u<4;u++){
        __half2 hv[4];
        #pragma unroll
        for (int k=0;k<4;k++)
            hv[k] = tile[swz((unsigned)k | (t<<2) | ((unsigned)u<<11))];
        *reinterpret_cast<uint4*>(hp + ((t<<2) | ((unsigned)u<<11) | (outer<<13))) =
            *reinterpret_cast<uint4*>(hv);
    }
}

// ---------------- P2 k_fin (B-type, outer = f10..12, READ, no LDS tile) — R14 verbatim
__global__ __launch_bounds__(256) void k_fin(const float* __restrict__ xg,
                                             const float* __restrict__ pg,
                                             const __half2* __restrict__ st,
                                             float* __restrict__ outg)
{
    __shared__ float cN[16], sN[16];
    __shared__ float snp, csp;
    __shared__ float red[4][3];
    const int tid = threadIdx.x;
    const int b = blockIdx.x >> 3;
    const unsigned outer = blockIdx.x & 7u;        // f bits 10..12
    if (tid < 16){
        int j=tid, q=15-j;
        float th = 0.5f*(xg[b*16+q]*PI_F + pg[64 + q]);      // Ry3
        float s,c; __sincosf(th,&s,&c);
        cN[j]=c; sN[j]=s;
    }
    if (tid==16){ float phi = 0.5f*pg[48 + 0]; float s,c; __sincosf(phi,&s,&c); snp=s; csp=c; }
    __syncthreads();
    const unsigned t = tid;
    const __half2* sp = st + ((size_t)b<<16);
    float2 a[32];
    #pragma unroll
    for (int u=0;u<8;u++){
        unsigned fb = (t<<2) | (outer<<10) | ((unsigned)u<<13);
        uint4 raw = *reinterpret_cast<const uint4*>(sp + fb);
        const __half2* hv = reinterpret_cast<const __half2*>(&raw);
        a[4*u+0] = __half22float2(hv[0]);
        a[4*u+1] = __half22float2(hv[1]);
        a[4*u+2] = __half22float2(hv[2]);
        a[4*u+3] = __half22float2(hv[3]);
    }
    // CN2(0->15): ctrl f0 = i0, tgt f15 = i4
    #pragma unroll
    for (int j=0;j<32;j++){ if (j&16) continue; if (j&1){ float2 tm=a[j]; a[j]=a[j|16]; a[j|16]=tm; } }
    // Rz2(f15)
    #pragma unroll
    for (int j=0;j<32;j++){
        float sn = ((j>>4)&1)? snp : -snp;
        float2 v=a[j];
        a[j]=make_float2(v.x*csp - v.y*sn, v.x*sn + v.y*csp);
    }
    #pragma unroll
    for (int j=0;j<32;j++){ if (j&1)  continue; ry_pair(a[j],a[j|1] ,cN[0] ,sN[0]);  }
    #pragma unroll
    for (int j=0;j<32;j++){ if (j&4)  continue; ry_pair(a[j],a[j|4] ,cN[13],sN[13]); }
    #pragma unroll
    for (int j=0;j<32;j++){ if (j&8)  continue; ry_pair(a[j],a[j|8] ,cN[14],sN[14]); }
    #pragma unroll
    for (int j=0;j<32;j++){ if (j&16) continue; ry_pair(a[j],a[j|16],cN[15],sN[15]); }
    const int pto = (__popc(t) + __popc(outer)) & 1;   // parity(f2..f12)
    float v0=0.f, v1=0.f, v2=0.f;
    #pragma unroll
    for (int i=0;i<32;i++){
        const int i0=i&1, i1=(i>>1)&1, i2=(i>>2)&1, i3=(i>>3)&1, i4=(i>>4)&1;
        const float pr = a[i].x*a[i].x + a[i].y*a[i].y;
        v0 += (i0^i1^i2^i3^pto)? -pr : pr;   // parity(f0..f14)
        v1 += (i3^i4)?           -pr : pr;   // f14^f15
        v2 += (i2^i3^i4)?        -pr : pr;   // f13^f14^f15
    }
    #pragma unroll
    for (int off=32; off>0; off>>=1){
        v0 += __shfl_down(v0, off);
        v1 += __shfl_down(v1, off);
        v2 += __shfl_down(v2, off);
    }
    const int wv = tid>>6, ln = tid&63;
    if (ln==0){ red[wv][0]=v0; red[wv][1]=v1; red[wv][2]=v2; }
    __syncthreads();
    if (tid<3){
        float s = red[0][tid]+red[1][tid]+red[2][tid]+red[3][tid];
        atomicAdd(&outg[b*3+tid], s);
    }
}

extern "C" void kernel_launch(void* const* d_in, const int* in_sizes, int n_in,
                              void* d_out, int out_size, void* d_ws, size_t ws_size,
                              hipStream_t stream)
{
    const float* x = (const float*)d_in[0];
    const float* params = (const float*)d_in[1];
    float* out = (float*)d_out;
    __half2* st = (__half2*)d_ws;
    const int B = in_sizes[0] / 16;

    hipMemsetAsync(d_out, 0, (size_t)out_size*sizeof(float), stream);

    const size_t per = (size_t)65536 * sizeof(__half2);  // 256 KB per batch element
    int chunk = (int)(ws_size / per);
    if (chunk > 512) chunk = 512;                        // 512 elem = 134 MB < L3
    if (chunk < 1) chunk = 1;
    if (chunk > B) chunk = B;
    for (int b0=0; b0<B; b0+=chunk){
        const int nb = (B-b0 < chunk) ? (B-b0) : chunk;
        const float* xb = x + (size_t)b0*16;
        float* ob = out + (size_t)b0*3;
        hipLaunchKernelGGL(k_all, dim3(nb*8), dim3(512), 0, stream, xb, params, st);
        hipLaunchKernelGGL(k_fin, dim3(nb*8), dim3(256), 0, stream, xb, params, st, ob);
    }
}

// Round 16
// 139.740 us; speedup vs baseline: 2.3794x; 1.2229x over previous
//
#include <hip/hip_runtime.h>
#include <hip/hip_bf16.h>
#include <hip/hip_fp16.h>

#define PI_F 3.14159265f

// Flat index convention: state.reshape((2,)*16) => qubit q <-> flat bit j = 15-q.
// Per layer: Ry(all f), CNOT chain (15->14),(14->13),...,(1->0),(0->15), Rz(all f).
// Measurement <Z_q> q=0,1,2 -> flat bits 15,14,13.
//
// 2-pass structure, state as __half2 (4 B/amp) end-to-end in P1:
//   P1 k_all (outer=f13..15, 512 thr, 16 amps/thr, WRITE-only): R15-verified
//     schedule/layouts; NEW: every gate computed in PACKED fp16 (v_pk_fma_f16)
//     on __half2 (re,im) amps — ry_pair 8->4 ops, Rz-cmul 6->3 ops, zero cvt
//     at LDS boundaries.  Generation stays f32, packs once.  CNOTs exact.
//   P2 k_fin (outer=f10..12, 256 thr, READ-only, R14/R15-verbatim, f32 math).
// Single chunk of 512 elements: 134 MB < 256 MB L3 -> handoff L3-resident.
// Precision: ~60 fp16 rounding events, measured scaling sqrt(n)*2.4e-4 ->
// ~1.9e-3; threshold 3.9e-3.

__device__ __forceinline__ unsigned swz(unsigned l){ return l ^ ((l>>5)&31u); }

__device__ __forceinline__ float2 cmul(float2 a, float2 b){
    return make_float2(a.x*b.x - a.y*b.y, a.x*b.y + a.y*b.x);
}

__device__ __forceinline__ void ry_pair(float2& A0, float2& A1, float c, float s){
    float2 a0=A0, a1=A1;
    A0 = make_float2(c*a0.x - s*a1.x, c*a0.y - s*a1.y);
    A1 = make_float2(s*a0.x + c*a1.x, s*a0.y + c*a1.y);
}

// packed-fp16 helpers ------------------------------------------------------
__device__ __forceinline__ __half2 h2swap(__half2 v){      // (re,im)->(im,re)
    unsigned u = *reinterpret_cast<unsigned*>(&v);
    u = (u>>16) | (u<<16);
    return *reinterpret_cast<__half2*>(&u);
}
__device__ __forceinline__ void ry_h(__half2& A0, __half2& A1,
                                     __half2 c2, __half2 s2, __half2 ns2){
    __half2 n0 = __hfma2(ns2, A1, __hmul2(c2, A0));        // c*a0 - s*a1
    __half2 n1 = __hfma2(s2,  A0, __hmul2(c2, A1));        // s*a0 + c*a1
    A0 = n0; A1 = n1;
}
__device__ __forceinline__ __half2 crot_h(__half2 v, __half2 wxx, __half2 wyn){
    // v * (wx + i*wy); wxx=(wx,wx), wyn=(-wy,wy)
    return __hfma2(v, wxx, __hmul2(h2swap(v), wyn));
}

#define RYH(BIT, F) { const __half2 c2=__float2half2_rn(c##F), s2=__float2half2_rn(s##F), ns2=__hneg2(s2); \
    _Pragma("unroll") for (int j=0;j<16;j++){ if (j&(BIT)) continue; ry_h(h[j],h[j|(BIT)],c2,s2,ns2);} }

// ---------------- P1: full generation + layer2(- (0->15),Rz2(f15)) + Ry3(1..12)
__global__ __launch_bounds__(512, 4) void k_all(const float* __restrict__ xg,
                                                const float* __restrict__ pg,
                                                __half2* __restrict__ st)
{
    __shared__ __half2 tile[8192];   // 32 KB
    __shared__ float cA[16], sA[16], cB[16], sB[16], cC[16], sC[16], phz1[16], phz2[16];
    __shared__ float2 K4[4], D1[16];
    __shared__ __half2 E2Ax[16], E2Ay[16], E2Bx[8], E2By[8],
                       E2Cx[8], E2Cy[8], E2Dx[8], E2Dy[8];
    const int tid = threadIdx.x;
    const int b = blockIdx.x >> 3;
    const unsigned outer = blockIdx.x & 7u;        // f13..15 (post-fold basis)

    // ---- stage 1: angle tables
    if (tid < 16){
        int j = tid, q = 15 - j;
        float th = 0.5f*(xg[b*16+q]*PI_F + pg[q]);           // Ry1
        __sincosf(th, &sA[j], &cA[j]);
    } else if (tid < 32){
        int j = tid-16, q = 15 - j;
        float th = 0.5f*(xg[b*16+q]*PI_F + pg[32+q]);        // Ry2
        __sincosf(th, &sB[j], &cB[j]);
    } else if (tid < 48){
        int j = tid-32, q = 15 - j;
        float th = 0.5f*(xg[b*16+q]*PI_F + pg[64+q]);        // Ry3
        __sincosf(th, &sC[j], &cC[j]);
    } else if (tid < 64){
        int j = tid-48, q = 15 - j;
        phz1[j] = 0.5f*pg[16+q];                              // Rz1
    } else if (tid < 80){
        int j = tid-64, q = 15 - j;
        phz2[j] = 0.5f*pg[48+q];                              // Rz2
    }
    __syncthreads();
    // ---- stage 2: block-uniform tables (R6/R8-verified values; E2* packed)
    if (tid < 4){
        const unsigned o13=outer&1u, o14=(outer>>1)&1u, o15=(outer>>2)&1u;
        const unsigned h13=o13^o14, h14=o14^o15, h15=o15;
        const int f0b=(tid>>1)&1, f12b=tid&1;
        float Kr=0.f, Ki=0.f;
        #pragma unroll
        for (int g=0; g<8; ++g){
            const unsigned g13=g&1u, g14=(g>>1)&1u, g15=(g>>2)&1u;
            float w;
            w  = (h13==g13)? cB[13] : (h13? sB[13] : -sB[13]);
            w *= (h14==g14)? cB[14] : (h14? sB[14] : -sB[14]);
            w *= (h15==g15)? cB[15] : (h15? sB[15] : -sB[15]);
            w *= (f12b^(int)g13)?          sA[12]:cA[12];
            w *= ((int)(g13^g14))?         sA[13]:cA[13];
            w *= ((int)g14^f0b^(int)g15)?  sA[14]:cA[14];
            w *= (f0b^(int)g15)?           sA[15]:cA[15];
            float phg = (g13? phz1[13]:-phz1[13]) + (g14? phz1[14]:-phz1[14])
                      + (g15? phz1[15]:-phz1[15]);
            float sn,cs; __sincosf(phg,&sn,&cs);
            Kr += w*cs; Ki += w*sn;
        }
        K4[tid] = make_float2(Kr,Ki);
    } else if (tid>=16 && tid<32){
        const int ii = tid-16;  // Rz1 deltas over f9..12
        float d=0.f;
        #pragma unroll
        for (int j=0;j<4;j++) d += ((ii>>j)&1)? phz1[9+j]:-phz1[9+j];
        float sn,cs; __sincosf(d,&sn,&cs); D1[ii]=make_float2(cs,sn);
    } else if (tid>=32 && tid<48){
        const int ii = tid-32;  // Rz2 over f9..12
        float d=0.f;
        #pragma unroll
        for (int j=0;j<4;j++) d += ((ii>>j)&1)? phz2[9+j]:-phz2[9+j];
        float sn,cs; __sincosf(d,&sn,&cs);
        E2Ax[ii]=__float2half2_rn(cs);
        E2Ay[ii]=__halves2half2(__float2half(-sn), __float2half(sn));
    } else if (tid>=48 && tid<56){
        const int ii = tid-48;  // Rz2 over f6..8
        float d=0.f;
        #pragma unroll
        for (int j=0;j<3;j++) d += ((ii>>j)&1)? phz2[6+j]:-phz2[6+j];
        float sn,cs; __sincosf(d,&sn,&cs);
        E2Bx[ii]=__float2half2_rn(cs);
        E2By[ii]=__halves2half2(__float2half(-sn), __float2half(sn));
    } else if (tid>=56 && tid<64){
        const int ii = tid-56;  // Rz2 over f3..5
        float d=0.f;
        #pragma unroll
        for (int j=0;j<3;j++) d += ((ii>>j)&1)? phz2[3+j]:-phz2[3+j];
        float sn,cs; __sincosf(d,&sn,&cs);
        E2Cx[ii]=__float2half2_rn(cs);
        E2Cy[ii]=__halves2half2(__float2half(-sn), __float2half(sn));
    } else if (tid>=64 && tid<72){
        const int ii = tid-64;  // Rz2 over f0..2 + uniform f13,f14
        float d=0.f;
        #pragma unroll
        for (int j=0;j<3;j++) d += ((ii>>j)&1)? phz2[j]:-phz2[j];
        d += (outer&1u)?      phz2[13]:-phz2[13];
        d += ((outer>>1)&1u)? phz2[14]:-phz2[14];
        float sn,cs; __sincosf(d,&sn,&cs);
        E2Dx[ii]=__float2half2_rn(cs);
        E2Dy[ii]=__halves2half2(__float2half(-sn), __float2half(sn));
    }
    __syncthreads();

    const unsigned t = tid;                 // trip A: t = f0..8 (9 bits)
    __half2 h[16];
    // ---- Trip A generation (f32, R8-verified), pack to half2
    {
        float base_t = 1.0f;
        #pragma unroll
        for (int j=0;j<8;j++){
            int v = (int)(((t>>j)^(t>>(j+1)))&1u);           // b_pre[j]=f_j^f_{j+1}
            base_t *= v? sA[j]:cA[j];
        }
        float pht = 0.f;
        #pragma unroll
        for (int j=0;j<9;j++) pht += ((t>>j)&1u)? phz1[j]:-phz1[j];
        float Ety,Etx; __sincosf(pht,&Ety,&Etx);
        const float2 Et = make_float2(Etx,Ety);
        const unsigned t0 = t&1u;
        const float2 EK0 = cmul(Et, K4[t0<<1]);
        const float2 EK1 = cmul(Et, K4[(t0<<1)|1u]);
        const int t8 = (int)((t>>8)&1u);
        #pragma unroll
        for (int i=0;i<16;i++){
            const int i0=i&1, i1=(i>>1)&1, i2=(i>>2)&1, i3=(i>>3)&1;
            float pr = base_t;
            pr *= (t8^i0)? sA[8] :cA[8];                     // b_pre[8]=f8^f9
            pr *= (i0^i1)? sA[9] :cA[9];
            pr *= (i1^i2)? sA[10]:cA[10];
            pr *= (i2^i3)? sA[11]:cA[11];
            float2 w = cmul(D1[i], i3? EK1:EK0);
            h[i] = __float22half2_rn(make_float2(pr*w.x, pr*w.y));
        }
    }
    // Trip A gates: i0=f9,i1=f10,i2=f11,i3=f12   (packed fp16)
    { const float cF=cB[9],  sF=sB[9];  RYH(1, F) }
    { const float cF=cB[10], sF=sB[10]; RYH(2, F) }
    { const float cF=cB[11], sF=sB[11]; RYH(4, F) }
    { const float cF=cB[12], sF=sB[12]; RYH(8, F) }
    if (outer & 1u){  // CN2(13->12): ctrl f13=o13 (uniform), tgt i3
        #pragma unroll
        for (int j=0;j<16;j++){ if (j&8) continue; __half2 tm=h[j]; h[j]=h[j|8]; h[j|8]=tm; }
    }
    #pragma unroll
    for (int j=0;j<16;j++){ if (j&4) continue; if ((j>>3)&1){ __half2 tm=h[j]; h[j]=h[j|4]; h[j|4]=tm; } } // (12->11)
    #pragma unroll
    for (int j=0;j<16;j++){ if (j&2) continue; if ((j>>2)&1){ __half2 tm=h[j]; h[j]=h[j|2]; h[j|2]=tm; } } // (11->10)
    #pragma unroll
    for (int j=0;j<16;j++){ if (j&1) continue; if ((j>>1)&1){ __half2 tm=h[j]; h[j]=h[j|1]; h[j|1]=tm; } } // (10->9)
    #pragma unroll
    for (int i=0;i<16;i++) h[i] = crot_h(h[i], E2Ax[i], E2Ay[i]);   // Rz2(f9..12)
    { const float cF=cC[10], sF=sC[10]; RYH(2, F) }
    { const float cF=cC[11], sF=sC[11]; RYH(4, F) }
    { const float cF=cC[12], sF=sC[12]; RYH(8, F) }
    // ---- transpose A -> B
    #pragma unroll
    for (int i=0;i<16;i++) tile[swz(t | ((unsigned)i<<9))] = h[i];
    __syncthreads();
    #pragma unroll
    for (int i=0;i<16;i++) h[i] = tile[swz((t&63u) | ((unsigned)i<<6) | ((t>>6)<<10))];
    // Trip B: i0=f6,i1=f7,i2=f8,i3=f9 ; t&63=f0..5, t>>6=f10..12
    { const float cF=cB[6], sF=sB[6]; RYH(1, F) }
    { const float cF=cB[7], sF=sB[7]; RYH(2, F) }
    { const float cF=cB[8], sF=sB[8]; RYH(4, F) }
    #pragma unroll
    for (int j=0;j<16;j++){ if (j&4) continue; if ((j>>3)&1){ __half2 tm=h[j]; h[j]=h[j|4]; h[j|4]=tm; } } // (9->8)
    #pragma unroll
    for (int j=0;j<16;j++){ if (j&2) continue; if ((j>>2)&1){ __half2 tm=h[j]; h[j]=h[j|2]; h[j|2]=tm; } } // (8->7)
    #pragma unroll
    for (int j=0;j<16;j++){ if (j&1) continue; if ((j>>1)&1){ __half2 tm=h[j]; h[j]=h[j|1]; h[j|1]=tm; } } // (7->6)
    #pragma unroll
    for (int i=0;i<16;i++) h[i] = crot_h(h[i], E2Bx[i&7], E2By[i&7]);  // Rz2(f6..8)
    { const float cF=cC[7], sF=sC[7]; RYH(2, F) }
    { const float cF=cC[8], sF=sC[8]; RYH(4, F) }
    { const float cF=cC[9], sF=sC[9]; RYH(8, F) }
    // ---- transpose B -> C
    #pragma unroll
    for (int i=0;i<16;i++) tile[swz((t&63u) | ((unsigned)i<<6) | ((t>>6)<<10))] = h[i];
    __syncthreads();
    #pragma unroll
    for (int i=0;i<16;i++) h[i] = tile[swz((t&7u) | ((unsigned)i<<3) | ((t>>3)<<7))];
    // Trip C: i0=f3,i1=f4,i2=f5,i3=f6 ; t&7=f0..2, t>>3=f7..12
    { const float cF=cB[3], sF=sB[3]; RYH(1, F) }
    { const float cF=cB[4], sF=sB[4]; RYH(2, F) }
    { const float cF=cB[5], sF=sB[5]; RYH(4, F) }
    #pragma unroll
    for (int j=0;j<16;j++){ if (j&4) continue; if ((j>>3)&1){ __half2 tm=h[j]; h[j]=h[j|4]; h[j|4]=tm; } } // (6->5)
    #pragma unroll
    for (int j=0;j<16;j++){ if (j&2) continue; if ((j>>2)&1){ __half2 tm=h[j]; h[j]=h[j|2]; h[j|2]=tm; } } // (5->4)
    #pragma unroll
    for (int j=0;j<16;j++){ if (j&1) continue; if ((j>>1)&1){ __half2 tm=h[j]; h[j]=h[j|1]; h[j|1]=tm; } } // (4->3)
    #pragma unroll
    for (int i=0;i<16;i++) h[i] = crot_h(h[i], E2Cx[i&7], E2Cy[i&7]);  // Rz2(f3..5)
    { const float cF=cC[4], sF=sC[4]; RYH(2, F) }
    { const float cF=cC[5], sF=sC[5]; RYH(4, F) }
    { const float cF=cC[6], sF=sC[6]; RYH(8, F) }
    // ---- transpose C -> D
    #pragma unroll
    for (int i=0;i<16;i++) tile[swz((t&7u) | ((unsigned)i<<3) | ((t>>3)<<7))] = h[i];
    __syncthreads();
    #pragma unroll
    for (int i=0;i<16;i++) h[i] = tile[swz((unsigned)i | (t<<4))];
    // Trip D: i0=f0,i1=f1,i2=f2,i3=f3 ; t=f4..12
    { const float cF=cB[0], sF=sB[0]; RYH(1, F) }
    { const float cF=cB[1], sF=sB[1]; RYH(2, F) }
    { const float cF=cB[2], sF=sB[2]; RYH(4, F) }
    #pragma unroll
    for (int j=0;j<16;j++){ if (j&4) continue; if ((j>>3)&1){ __half2 tm=h[j]; h[j]=h[j|4]; h[j|4]=tm; } } // (3->2)
    #pragma unroll
    for (int j=0;j<16;j++){ if (j&2) continue; if ((j>>2)&1){ __half2 tm=h[j]; h[j]=h[j|2]; h[j|2]=tm; } } // (2->1)
    #pragma unroll
    for (int j=0;j<16;j++){ if (j&1) continue; if ((j>>1)&1){ __half2 tm=h[j]; h[j]=h[j|1]; h[j|1]=tm; } } // (1->0)
    #pragma unroll
    for (int i=0;i<16;i++) h[i] = crot_h(h[i], E2Dx[i&7], E2Dy[i&7]);  // Rz2(f0..2,f13,f14)
    { const float cF=cC[1], sF=sC[1]; RYH(2, F) }
    { const float cF=cC[2], sF=sC[2]; RYH(4, F) }
    { const float cF=cC[3], sF=sC[3]; RYH(8, F) }
    // ---- transpose D -> store layout (read: (i&3)|(t<<2)|((i>>2)<<11), R14-verified)
    __syncthreads();
    #pragma unroll
    for (int i=0;i<16;i++) tile[swz((unsigned)i | (t<<4))] = h[i];
    __syncthreads();
    __half2* hp = st + ((size_t)b<<16);
    #pragma unroll
    for (int u=0;u<4;u++){
        __half2 hv[4];
        #pragma unroll
        for (int k=0;k<4;k++)
            hv[k] = tile[swz((unsigned)k | (t<<2) | ((unsigned)u<<11))];
        *reinterpret_cast<uint4*>(hp + ((t<<2) | ((unsigned)u<<11) | (outer<<13))) =
            *reinterpret_cast<uint4*>(hv);
    }
}

// ---------------- P2 k_fin (B-type, outer = f10..12, READ, no LDS tile) — R14 verbatim
__global__ __launch_bounds__(256) void k_fin(const float* __restrict__ xg,
                                             const float* __restrict__ pg,
                                             const __half2* __restrict__ st,
                                             float* __restrict__ outg)
{
    __shared__ float cN[16], sN[16];
    __shared__ float snp, csp;
    __shared__ float red[4][3];
    const int tid = threadIdx.x;
    const int b = blockIdx.x >> 3;
    const unsigned outer = blockIdx.x & 7u;        // f bits 10..12
    if (tid < 16){
        int j=tid, q=15-j;
        float th = 0.5f*(xg[b*16+q]*PI_F + pg[64 + q]);      // Ry3
        float s,c; __sincosf(th,&s,&c);
        cN[j]=c; sN[j]=s;
    }
    if (tid==16){ float phi = 0.5f*pg[48 + 0]; float s,c; __sincosf(phi,&s,&c); snp=s; csp=c; }
    __syncthreads();
    const unsigned t = tid;
    const __half2* sp = st + ((size_t)b<<16);
    float2 a[32];
    #pragma unroll
    for (int u=0;u<8;u++){
        unsigned fb = (t<<2) | (outer<<10) | ((unsigned)u<<13);
        uint4 raw = *reinterpret_cast<const uint4*>(sp + fb);
        const __half2* hv = reinterpret_cast<const __half2*>(&raw);
        a[4*u+0] = __half22float2(hv[0]);
        a[4*u+1] = __half22float2(hv[1]);
        a[4*u+2] = __half22float2(hv[2]);
        a[4*u+3] = __half22float2(hv[3]);
    }
    // CN2(0->15): ctrl f0 = i0, tgt f15 = i4
    #pragma unroll
    for (int j=0;j<32;j++){ if (j&16) continue; if (j&1){ float2 tm=a[j]; a[j]=a[j|16]; a[j|16]=tm; } }
    // Rz2(f15)
    #pragma unroll
    for (int j=0;j<32;j++){
        float sn = ((j>>4)&1)? snp : -snp;
        float2 v=a[j];
        a[j]=make_float2(v.x*csp - v.y*sn, v.x*sn + v.y*csp);
    }
    #pragma unroll
    for (int j=0;j<32;j++){ if (j&1)  continue; ry_pair(a[j],a[j|1] ,cN[0] ,sN[0]);  }
    #pragma unroll
    for (int j=0;j<32;j++){ if (j&4)  continue; ry_pair(a[j],a[j|4] ,cN[13],sN[13]); }
    #pragma unroll
    for (int j=0;j<32;j++){ if (j&8)  continue; ry_pair(a[j],a[j|8] ,cN[14],sN[14]); }
    #pragma unroll
    for (int j=0;j<32;j++){ if (j&16) continue; ry_pair(a[j],a[j|16],cN[15],sN[15]); }
    const int pto = (__popc(t) + __popc(outer)) & 1;   // parity(f2..f12)
    float v0=0.f, v1=0.f, v2=0.f;
    #pragma unroll
    for (int i=0;i<32;i++){
        const int i0=i&1, i1=(i>>1)&1, i2=(i>>2)&1, i3=(i>>3)&1, i4=(i>>4)&1;
        const float pr = a[i].x*a[i].x + a[i].y*a[i].y;
        v0 += (i0^i1^i2^i3^pto)? -pr : pr;   // parity(f0..f14)
        v1 += (i3^i4)?           -pr : pr;   // f14^f15
        v2 += (i2^i3^i4)?        -pr : pr;   // f13^f14^f15
    }
    #pragma unroll
    for (int off=32; off>0; off>>=1){
        v0 += __shfl_down(v0, off);
        v1 += __shfl_down(v1, off);
        v2 += __shfl_down(v2, off);
    }
    const int wv = tid>>6, ln = tid&63;
    if (ln==0){ red[wv][0]=v0; red[wv][1]=v1; red[wv][2]=v2; }
    __syncthreads();
    if (tid<3){
        float s = red[0][tid]+red[1][tid]+red[2][tid]+red[3][tid];
        atomicAdd(&outg[b*3+tid], s);
    }
}

extern "C" void kernel_launch(void* const* d_in, const int* in_sizes, int n_in,
                              void* d_out, int out_size, void* d_ws, size_t ws_size,
                              hipStream_t stream)
{
    const float* x = (const float*)d_in[0];
    const float* params = (const float*)d_in[1];
    float* out = (float*)d_out;
    __half2* st = (__half2*)d_ws;
    const int B = in_sizes[0] / 16;

    hipMemsetAsync(d_out, 0, (size_t)out_size*sizeof(float), stream);

    const size_t per = (size_t)65536 * sizeof(__half2);  // 256 KB per batch element
    int chunk = (int)(ws_size / per);
    if (chunk > 512) chunk = 512;                        // 512 elem = 134 MB < L3
    if (chunk < 1) chunk = 1;
    if (chunk > B) chunk = B;
    for (int b0=0; b0<B; b0+=chunk){
        const int nb = (B-b0 < chunk) ? (B-b0) : chunk;
        const float* xb = x + (size_t)b0*16;
        float* ob = out + (size_t)b0*3;
        hipLaunchKernelGGL(k_all, dim3(nb*8), dim3(512), 0, stream, xb, params, st);
        hipLaunchKernelGGL(k_fin, dim3(nb*8), dim3(256), 0, stream, xb, params, st, ob);
    }
}

// Round 17
// 132.069 us; speedup vs baseline: 2.5176x; 1.0581x over previous
//
#include <hip/hip_runtime.h>
#include <hip/hip_bf16.h>
#include <hip/hip_fp16.h>

#define PI_F 3.14159265f

// Flat index convention: state.reshape((2,)*16) => qubit q <-> flat bit j = 15-q.
// Per layer: Ry(all f), CNOT chain (15->14),(14->13),...,(1->0),(0->15), Rz(all f).
// Measurement <Z_q> q=0,1,2 -> flat bits 15,14,13.
//
// 2-pass structure, state as __half2 (4 B/amp) end-to-end:
//   P1 k_all (outer=f13..15, 512 thr, 16 amps/thr, WRITE-only): R16-verified
//     schedule/layouts/packed-fp16 gates.  NEW: generation via 64-entry V table
//     (V[(t8<<5)|(t0<<4)|i] = G(t8,i) * cmul(D1[i], K4[t0,i3]) -- associativity
//     regrouping of the R8-verified expression); inner loop = 1 LDS read +
//     cmul + pack (was ~16 f32 ops/amp).  Stage 2 split: 2a builds K4/E2*,
//     barrier, 2b builds V.
//   P2 k_fin (outer=f10..12, 256 thr, READ-only): R14-verified layout/algebra;
//     NEW: gates in packed fp16 (state already fp16-quantized), f32 only for
//     |amp|^2 accumulation + reduction.
// Single chunk of 512 elements: 134 MB < 256 MB L3 -> handoff L3-resident.
// Precision: ~65 fp16 rounding events -> ~1-1.7e-3; threshold 3.9e-3.

__device__ __forceinline__ unsigned swz(unsigned l){ return l ^ ((l>>5)&31u); }

__device__ __forceinline__ float2 cmul(float2 a, float2 b){
    return make_float2(a.x*b.x - a.y*b.y, a.x*b.y + a.y*b.x);
}

// packed-fp16 helpers ------------------------------------------------------
__device__ __forceinline__ __half2 h2swap(__half2 v){      // (re,im)->(im,re)
    unsigned u = *reinterpret_cast<unsigned*>(&v);
    u = (u>>16) | (u<<16);
    return *reinterpret_cast<__half2*>(&u);
}
__device__ __forceinline__ void ry_h(__half2& A0, __half2& A1,
                                     __half2 c2, __half2 s2, __half2 ns2){
    __half2 n0 = __hfma2(ns2, A1, __hmul2(c2, A0));        // c*a0 - s*a1
    __half2 n1 = __hfma2(s2,  A0, __hmul2(c2, A1));        // s*a0 + c*a1
    A0 = n0; A1 = n1;
}
__device__ __forceinline__ __half2 crot_h(__half2 v, __half2 wxx, __half2 wyn){
    // v * (wx + i*wy); wxx=(wx,wx), wyn=(-wy,wy)
    return __hfma2(v, wxx, __hmul2(h2swap(v), wyn));
}

#define RYH(BIT, F) { const __half2 c2=__float2half2_rn(c##F), s2=__float2half2_rn(s##F), ns2=__hneg2(s2); \
    _Pragma("unroll") for (int j=0;j<16;j++){ if (j&(BIT)) continue; ry_h(h[j],h[j|(BIT)],c2,s2,ns2);} }
#define RYH32(BIT, CC, SS) { const __half2 c2=__float2half2_rn(CC), s2=__float2half2_rn(SS), ns2=__hneg2(s2); \
    _Pragma("unroll") for (int j=0;j<32;j++){ if (j&(BIT)) continue; ry_h(h[j],h[j|(BIT)],c2,s2,ns2);} }

// ---------------- P1: full generation + layer2(- (0->15),Rz2(f15)) + Ry3(1..12)
__global__ __launch_bounds__(512, 4) void k_all(const float* __restrict__ xg,
                                                const float* __restrict__ pg,
                                                __half2* __restrict__ st)
{
    __shared__ __half2 tile[8192];   // 32 KB
    __shared__ float cA[16], sA[16], cB[16], sB[16], cC[16], sC[16], phz1[16], phz2[16];
    __shared__ float2 K4[4], V[64];
    __shared__ __half2 E2Ax[16], E2Ay[16], E2Bx[8], E2By[8],
                       E2Cx[8], E2Cy[8], E2Dx[8], E2Dy[8];
    const int tid = threadIdx.x;
    const int b = blockIdx.x >> 3;
    const unsigned outer = blockIdx.x & 7u;        // f13..15 (post-fold basis)

    // ---- stage 1: angle tables
    if (tid < 16){
        int j = tid, q = 15 - j;
        float th = 0.5f*(xg[b*16+q]*PI_F + pg[q]);           // Ry1
        __sincosf(th, &sA[j], &cA[j]);
    } else if (tid < 32){
        int j = tid-16, q = 15 - j;
        float th = 0.5f*(xg[b*16+q]*PI_F + pg[32+q]);        // Ry2
        __sincosf(th, &sB[j], &cB[j]);
    } else if (tid < 48){
        int j = tid-32, q = 15 - j;
        float th = 0.5f*(xg[b*16+q]*PI_F + pg[64+q]);        // Ry3
        __sincosf(th, &sC[j], &cC[j]);
    } else if (tid < 64){
        int j = tid-48, q = 15 - j;
        phz1[j] = 0.5f*pg[16+q];                              // Rz1
    } else if (tid < 80){
        int j = tid-64, q = 15 - j;
        phz2[j] = 0.5f*pg[48+q];                              // Rz2
    }
    __syncthreads();
    // ---- stage 2a: K4 + packed Rz2 tables (R6/R8/R16-verified values)
    if (tid < 4){
        const unsigned o13=outer&1u, o14=(outer>>1)&1u, o15=(outer>>2)&1u;
        const unsigned h13=o13^o14, h14=o14^o15, h15=o15;
        const int f0b=(tid>>1)&1, f12b=tid&1;
        float Kr=0.f, Ki=0.f;
        #pragma unroll
        for (int g=0; g<8; ++g){
            const unsigned g13=g&1u, g14=(g>>1)&1u, g15=(g>>2)&1u;
            float w;
            w  = (h13==g13)? cB[13] : (h13? sB[13] : -sB[13]);
            w *= (h14==g14)? cB[14] : (h14? sB[14] : -sB[14]);
            w *= (h15==g15)? cB[15] : (h15? sB[15] : -sB[15]);
            w *= (f12b^(int)g13)?          sA[12]:cA[12];
            w *= ((int)(g13^g14))?         sA[13]:cA[13];
            w *= ((int)g14^f0b^(int)g15)?  sA[14]:cA[14];
            w *= (f0b^(int)g15)?           sA[15]:cA[15];
            float phg = (g13? phz1[13]:-phz1[13]) + (g14? phz1[14]:-phz1[14])
                      + (g15? phz1[15]:-phz1[15]);
            float sn,cs; __sincosf(phg,&sn,&cs);
            Kr += w*cs; Ki += w*sn;
        }
        K4[tid] = make_float2(Kr,Ki);
    } else if (tid>=32 && tid<48){
        const int ii = tid-32;  // Rz2 over f9..12
        float d=0.f;
        #pragma unroll
        for (int j=0;j<4;j++) d += ((ii>>j)&1)? phz2[9+j]:-phz2[9+j];
        float sn,cs; __sincosf(d,&sn,&cs);
        E2Ax[ii]=__float2half2_rn(cs);
        E2Ay[ii]=__halves2half2(__float2half(-sn), __float2half(sn));
    } else if (tid>=48 && tid<56){
        const int ii = tid-48;  // Rz2 over f6..8
        float d=0.f;
        #pragma unroll
        for (int j=0;j<3;j++) d += ((ii>>j)&1)? phz2[6+j]:-phz2[6+j];
        float sn,cs; __sincosf(d,&sn,&cs);
        E2Bx[ii]=__float2half2_rn(cs);
        E2By[ii]=__halves2half2(__float2half(-sn), __float2half(sn));
    } else if (tid>=56 && tid<64){
        const int ii = tid-56;  // Rz2 over f3..5
        float d=0.f;
        #pragma unroll
        for (int j=0;j<3;j++) d += ((ii>>j)&1)? phz2[3+j]:-phz2[3+j];
        float sn,cs; __sincosf(d,&sn,&cs);
        E2Cx[ii]=__float2half2_rn(cs);
        E2Cy[ii]=__halves2half2(__float2half(-sn), __float2half(sn));
    } else if (tid>=64 && tid<72){
        const int ii = tid-64;  // Rz2 over f0..2 + uniform f13,f14
        float d=0.f;
        #pragma unroll
        for (int j=0;j<3;j++) d += ((ii>>j)&1)? phz2[j]:-phz2[j];
        d += (outer&1u)?      phz2[13]:-phz2[13];
        d += ((outer>>1)&1u)? phz2[14]:-phz2[14];
        float sn,cs; __sincosf(d,&sn,&cs);
        E2Dx[ii]=__float2half2_rn(cs);
        E2Dy[ii]=__halves2half2(__float2half(-sn), __float2half(sn));
    }
    __syncthreads();
    // ---- stage 2b: V table (needs K4).  V[(t8<<5)|(t0<<4)|i] =
    //   G(t8,i) * cmul(D1(i), K4[(t0<<1)|i3])   [regrouped R8 gen expression]
    if (tid < 64){
        const int i  = tid & 15;
        const int t0b = (tid>>4)&1, t8b = (tid>>5)&1;
        const int i0=i&1, i1=(i>>1)&1, i2=(i>>2)&1, i3=(i>>3)&1;
        float G = ((t8b^i0)? sA[8] :cA[8])
                * ((i0^i1)?  sA[9] :cA[9])
                * ((i1^i2)?  sA[10]:cA[10])
                * ((i2^i3)?  sA[11]:cA[11]);
        float d = 0.f;
        #pragma unroll
        for (int j=0;j<4;j++) d += ((i>>j)&1)? phz1[9+j]:-phz1[9+j];
        float sn,cs; __sincosf(d,&sn,&cs);
        float2 K = K4[(t0b<<1)|i3];
        V[tid] = make_float2(G*(cs*K.x - sn*K.y), G*(cs*K.y + sn*K.x));
    }
    __syncthreads();

    const unsigned t = tid;                 // trip A: t = f0..8 (9 bits)
    __half2 h[16];
    // ---- Trip A generation via V table
    {
        float base_t = 1.0f;
        #pragma unroll
        for (int j=0;j<8;j++){
            int v = (int)(((t>>j)^(t>>(j+1)))&1u);           // b_pre[j]=f_j^f_{j+1}
            base_t *= v? sA[j]:cA[j];
        }
        float pht = 0.f;
        #pragma unroll
        for (int j=0;j<9;j++) pht += ((t>>j)&1u)? phz1[j]:-phz1[j];
        float Ey,Ex; __sincosf(pht,&Ey,&Ex);
        Ex *= base_t; Ey *= base_t;                          // Et' = base_t * e^{i*pht}
        const float2* Vb = V + ((((t>>8)&1u)<<5) | ((t&1u)<<4));
        #pragma unroll
        for (int i=0;i<16;i++){
            const float2 v = Vb[i];
            h[i] = __float22half2_rn(make_float2(Ex*v.x - Ey*v.y, Ex*v.y + Ey*v.x));
        }
    }
    // Trip A gates: i0=f9,i1=f10,i2=f11,i3=f12   (packed fp16, R16-verified)
    { const float cF=cB[9],  sF=sB[9];  RYH(1, F) }
    { const float cF=cB[10], sF=sB[10]; RYH(2, F) }
    { const float cF=cB[11], sF=sB[11]; RYH(4, F) }
    { const float cF=cB[12], sF=sB[12]; RYH(8, F) }
    if (outer & 1u){  // CN2(13->12): ctrl f13=o13 (uniform), tgt i3
        #pragma unroll
        for (int j=0;j<16;j++){ if (j&8) continue; __half2 tm=h[j]; h[j]=h[j|8]; h[j|8]=tm; }
    }
    #pragma unroll
    for (int j=0;j<16;j++){ if (j&4) continue; if ((j>>3)&1){ __half2 tm=h[j]; h[j]=h[j|4]; h[j|4]=tm; } } // (12->11)
    #pragma unroll
    for (int j=0;j<16;j++){ if (j&2) continue; if ((j>>2)&1){ __half2 tm=h[j]; h[j]=h[j|2]; h[j|2]=tm; } } // (11->10)
    #pragma unroll
    for (int j=0;j<16;j++){ if (j&1) continue; if ((j>>1)&1){ __half2 tm=h[j]; h[j]=h[j|1]; h[j|1]=tm; } } // (10->9)
    #pragma unroll
    for (int i=0;i<16;i++) h[i] = crot_h(h[i], E2Ax[i], E2Ay[i]);   // Rz2(f9..12)
    { const float cF=cC[10], sF=sC[10]; RYH(2, F) }
    { const float cF=cC[11], sF=sC[11]; RYH(4, F) }
    { const float cF=cC[12], sF=sC[12]; RYH(8, F) }
    // ---- transpose A -> B
    #pragma unroll
    for (int i=0;i<16;i++) tile[swz(t | ((unsigned)i<<9))] = h[i];
    __syncthreads();
    #pragma unroll
    for (int i=0;i<16;i++) h[i] = tile[swz((t&63u) | ((unsigned)i<<6) | ((t>>6)<<10))];
    // Trip B: i0=f6,i1=f7,i2=f8,i3=f9 ; t&63=f0..5, t>>6=f10..12
    { const float cF=cB[6], sF=sB[6]; RYH(1, F) }
    { const float cF=cB[7], sF=sB[7]; RYH(2, F) }
    { const float cF=cB[8], sF=sB[8]; RYH(4, F) }
    #pragma unroll
    for (int j=0;j<16;j++){ if (j&4) continue; if ((j>>3)&1){ __half2 tm=h[j]; h[j]=h[j|4]; h[j|4]=tm; } } // (9->8)
    #pragma unroll
    for (int j=0;j<16;j++){ if (j&2) continue; if ((j>>2)&1){ __half2 tm=h[j]; h[j]=h[j|2]; h[j|2]=tm; } } // (8->7)
    #pragma unroll
    for (int j=0;j<16;j++){ if (j&1) continue; if ((j>>1)&1){ __half2 tm=h[j]; h[j]=h[j|1]; h[j|1]=tm; } } // (7->6)
    #pragma unroll
    for (int i=0;i<16;i++) h[i] = crot_h(h[i], E2Bx[i&7], E2By[i&7]);  // Rz2(f6..8)
    { const float cF=cC[7], sF=sC[7]; RYH(2, F) }
    { const float cF=cC[8], sF=sC[8]; RYH(4, F) }
    { const float cF=cC[9], sF=sC[9]; RYH(8, F) }
    // ---- transpose B -> C
    #pragma unroll
    for (int i=0;i<16;i++) tile[swz((t&63u) | ((unsigned)i<<6) | ((t>>6)<<10))] = h[i];
    __syncthreads();
    #pragma unroll
    for (int i=0;i<16;i++) h[i] = tile[swz((t&7u) | ((unsigned)i<<3) | ((t>>3)<<7))];
    // Trip C: i0=f3,i1=f4,i2=f5,i3=f6 ; t&7=f0..2, t>>3=f7..12
    { const float cF=cB[3], sF=sB[3]; RYH(1, F) }
    { const float cF=cB[4], sF=sB[4]; RYH(2, F) }
    { const float cF=cB[5], sF=sB[5]; RYH(4, F) }
    #pragma unroll
    for (int j=0;j<16;j++){ if (j&4) continue; if ((j>>3)&1){ __half2 tm=h[j]; h[j]=h[j|4]; h[j|4]=tm; } } // (6->5)
    #pragma unroll
    for (int j=0;j<16;j++){ if (j&2) continue; if ((j>>2)&1){ __half2 tm=h[j]; h[j]=h[j|2]; h[j|2]=tm; } } // (5->4)
    #pragma unroll
    for (int j=0;j<16;j++){ if (j&1) continue; if ((j>>1)&1){ __half2 tm=h[j]; h[j]=h[j|1]; h[j|1]=tm; } } // (4->3)
    #pragma unroll
    for (int i=0;i<16;i++) h[i] = crot_h(h[i], E2Cx[i&7], E2Cy[i&7]);  // Rz2(f3..5)
    { const float cF=cC[4], sF=sC[4]; RYH(2, F) }
    { const float cF=cC[5], sF=sC[5]; RYH(4, F) }
    { const float cF=cC[6], sF=sC[6]; RYH(8, F) }
    // ---- transpose C -> D
    #pragma unroll
    for (int i=0;i<16;i++) tile[swz((t&7u) | ((unsigned)i<<3) | ((t>>3)<<7))] = h[i];
    __syncthreads();
    #pragma unroll
    for (int i=0;i<16;i++) h[i] = tile[swz((unsigned)i | (t<<4))];
    // Trip D: i0=f0,i1=f1,i2=f2,i3=f3 ; t=f4..12
    { const float cF=cB[0], sF=sB[0]; RYH(1, F) }
    { const float cF=cB[1], sF=sB[1]; RYH(2, F) }
    { const float cF=cB[2], sF=sB[2]; RYH(4, F) }
    #pragma unroll
    for (int j=0;j<16;j++){ if (j&4) continue; if ((j>>3)&1){ __half2 tm=h[j]; h[j]=h[j|4]; h[j|4]=tm; } } // (3->2)
    #pragma unroll
    for (int j=0;j<16;j++){ if (j&2) continue; if ((j>>2)&1){ __half2 tm=h[j]; h[j]=h[j|2]; h[j|2]=tm; } } // (2->1)
    #pragma unroll
    for (int j=0;j<16;j++){ if (j&1) continue; if ((j>>1)&1){ __half2 tm=h[j]; h[j]=h[j|1]; h[j|1]=tm; } } // (1->0)
    #pragma unroll
    for (int i=0;i<16;i++) h[i] = crot_h(h[i], E2Dx[i&7], E2Dy[i&7]);  // Rz2(f0..2,f13,f14)
    { const float cF=cC[1], sF=sC[1]; RYH(2, F) }
    { const float cF=cC[2], sF=sC[2]; RYH(4, F) }
    { const float cF=cC[3], sF=sC[3]; RYH(8, F) }
    // ---- transpose D -> store layout (read: (i&3)|(t<<2)|((i>>2)<<11), R14-verified)
    __syncthreads();
    #pragma unroll
    for (int i=0;i<16;i++) tile[swz((unsigned)i | (t<<4))] = h[i];
    __syncthreads();
    __half2* hp = st + ((size_t)b<<16);
    #pragma unroll
    for (int u=0;u<4;u++){
        __half2 hv[4];
        #pragma unroll
        for (int k=0;k<4;k++)
            hv[k] = tile[swz((unsigned)k | (t<<2) | ((unsigned)u<<11))];
        *reinterpret_cast<uint4*>(hp + ((t<<2) | ((unsigned)u<<11) | (outer<<13))) =
            *reinterpret_cast<uint4*>(hv);
    }
}

// ---------------- P2 k_fin (B-type, outer = f10..12, READ, no LDS tile)
// R14-verified layout/algebra; gates in packed fp16.
__global__ __launch_bounds__(256) void k_fin(const float* __restrict__ xg,
                                             const float* __restrict__ pg,
                                             const __half2* __restrict__ st,
                                             float* __restrict__ outg)
{
    __shared__ float cN[16], sN[16];
    __shared__ float snp, csp;
    __shared__ float red[4][3];
    const int tid = threadIdx.x;
    const int b = blockIdx.x >> 3;
    const unsigned outer = blockIdx.x & 7u;        // f bits 10..12
    if (tid < 16){
        int j=tid, q=15-j;
        float th = 0.5f*(xg[b*16+q]*PI_F + pg[64 + q]);      // Ry3
        float s,c; __sincosf(th,&s,&c);
        cN[j]=c; sN[j]=s;
    }
    if (tid==16){ float phi = 0.5f*pg[48 + 0]; float s,c; __sincosf(phi,&s,&c); snp=s; csp=c; }
    __syncthreads();
    const unsigned t = tid;
    const __half2* sp = st + ((size_t)b<<16);
    __half2 h[32];
    #pragma unroll
    for (int u=0;u<8;u++){
        unsigned fb = (t<<2) | (outer<<10) | ((unsigned)u<<13);
        uint4 raw = *reinterpret_cast<const uint4*>(sp + fb);
        const __half2* hv = reinterpret_cast<const __half2*>(&raw);
        h[4*u+0]=hv[0]; h[4*u+1]=hv[1]; h[4*u+2]=hv[2]; h[4*u+3]=hv[3];
    }
    // CN2(0->15): ctrl f0 = i0, tgt f15 = i4 (exact swap)
    #pragma unroll
    for (int j=0;j<32;j++){ if (j&16) continue; if (j&1){ __half2 tm=h[j]; h[j]=h[j|16]; h[j|16]=tm; } }
    // Rz2(f15): angle = +-phi by i4   (packed)
    {
        const __half2 wxx = __float2half2_rn(csp);
        const __half2 wyp = __halves2half2(__float2half(-snp), __float2half(snp));   // +phi
        const __half2 wym = __halves2half2(__float2half( snp), __float2half(-snp));  // -phi
        #pragma unroll
        for (int j=0;j<32;j++) h[j] = crot_h(h[j], wxx, (j&16)? wyp : wym);
    }
    // Ry3(f0)=bit1 ; Ry3(f13)=bit4 ; Ry3(f14)=bit8 ; Ry3(f15)=bit16  (packed)
    RYH32(1,  cN[0],  sN[0])
    RYH32(4,  cN[13], sN[13])
    RYH32(8,  cN[14], sN[14])
    RYH32(16, cN[15], sN[15])
    // measurement (f32 accumulation)
    const int pto = (__popc(t) + __popc(outer)) & 1;   // parity(f2..f12)
    float v0=0.f, v1=0.f, v2=0.f;
    #pragma unroll
    for (int i=0;i<32;i++){
        const int i0=i&1, i1=(i>>1)&1, i2=(i>>2)&1, i3=(i>>3)&1, i4=(i>>4)&1;
        const float2 a = __half22float2(h[i]);
        const float pr = a.x*a.x + a.y*a.y;
        v0 += (i0^i1^i2^i3^pto)? -pr : pr;   // parity(f0..f14)
        v1 += (i3^i4)?           -pr : pr;   // f14^f15
        v2 += (i2^i3^i4)?        -pr : pr;   // f13^f14^f15
    }
    #pragma unroll
    for (int off=32; off>0; off>>=1){
        v0 += __shfl_down(v0, off);
        v1 += __shfl_down(v1, off);
        v2 += __shfl_down(v2, off);
    }
    const int wv = tid>>6, ln = tid&63;
    if (ln==0){ red[wv][0]=v0; red[wv][1]=v1; red[wv][2]=v2; }
    __syncthreads();
    if (tid<3){
        float s = red[0][tid]+red[1][tid]+red[2][tid]+red[3][tid];
        atomicAdd(&outg[b*3+tid], s);
    }
}

extern "C" void kernel_launch(void* const* d_in, const int* in_sizes, int n_in,
                              void* d_out, int out_size, void* d_ws, size_t ws_size,
                              hipStream_t stream)
{
    const float* x = (const float*)d_in[0];
    const float* params = (const float*)d_in[1];
    float* out = (float*)d_out;
    __half2* st = (__half2*)d_ws;
    const int B = in_sizes[0] / 16;

    hipMemsetAsync(d_out, 0, (size_t)out_size*sizeof(float), stream);

    const size_t per = (size_t)65536 * sizeof(__half2);  // 256 KB per batch element
    int chunk = (int)(ws_size / per);
    if (chunk > 512) chunk = 512;                        // 512 elem = 134 MB < L3
    if (chunk < 1) chunk = 1;
    if (chunk > B) chunk = B;
    for (int b0=0; b0<B; b0+=chunk){
        const int nb = (B-b0 < chunk) ? (B-b0) : chunk;
        const float* xb = x + (size_t)b0*16;
        float* ob = out + (size_t)b0*3;
        hipLaunchKernelGGL(k_all, dim3(nb*8), dim3(512), 0, stream, xb, params, st);
        hipLaunchKernelGGL(k_fin, dim3(nb*8), dim3(256), 0, stream, xb, params, st, ob);
    }
}

// Round 18
// 129.641 us; speedup vs baseline: 2.5648x; 1.0187x over previous
//
#include <hip/hip_runtime.h>
#include <hip/hip_bf16.h>
#include <hip/hip_fp16.h>

#define PI_F 3.14159265f

// Flat index convention: state.reshape((2,)*16) => qubit q <-> flat bit j = 15-q.
// Per layer: Ry(all f), CNOT chain (15->14),(14->13),...,(1->0),(0->15), Rz(all f).
// Measurement <Z_q> q=0,1,2 -> flat bits 15,14,13.
//
// 2-pass structure, state as __half2 (4 B/amp) end-to-end:
//   P1 k_all (outer=f13..15, 512 thr, 16 amps/thr, WRITE-only): R17-verified
//     V-table generation + packed-fp16 gates + 3 LDS transposes (A->B,B->C,C->D).
//     NEW vs R17: the D->S transpose is DELETED — trip-D layout is already
//     globally contiguous (thread t holds f = i|(t<<4)|(outer<<13), i=0..15 =
//     64 B), so we store 4 adjacent uint4 per lane; each wave covers a
//     contiguous 4 KB span (every cache line fully written).  k_fin layout
//     unchanged (canonical st[f]).
//   P2 k_fin (outer=f10..12, 256 thr, READ-only): R17-verbatim (packed fp16
//     gates, f32 |amp|^2 accumulation).
// Single chunk of 512 elements: 134 MB < 256 MB L3 -> handoff L3-resident.
// Precision: same event count as R17 (measured 9.8e-4); threshold 3.9e-3.

__device__ __forceinline__ unsigned swz(unsigned l){ return l ^ ((l>>5)&31u); }

__device__ __forceinline__ float2 cmul(float2 a, float2 b){
    return make_float2(a.x*b.x - a.y*b.y, a.x*b.y + a.y*b.x);
}

// packed-fp16 helpers ------------------------------------------------------
__device__ __forceinline__ __half2 h2swap(__half2 v){      // (re,im)->(im,re)
    unsigned u = *reinterpret_cast<unsigned*>(&v);
    u = (u>>16) | (u<<16);
    return *reinterpret_cast<__half2*>(&u);
}
__device__ __forceinline__ void ry_h(__half2& A0, __half2& A1,
                                     __half2 c2, __half2 s2, __half2 ns2){
    __half2 n0 = __hfma2(ns2, A1, __hmul2(c2, A0));        // c*a0 - s*a1
    __half2 n1 = __hfma2(s2,  A0, __hmul2(c2, A1));        // s*a0 + c*a1
    A0 = n0; A1 = n1;
}
__device__ __forceinline__ __half2 crot_h(__half2 v, __half2 wxx, __half2 wyn){
    // v * (wx + i*wy); wxx=(wx,wx), wyn=(-wy,wy)
    return __hfma2(v, wxx, __hmul2(h2swap(v), wyn));
}

#define RYH(BIT, F) { const __half2 c2=__float2half2_rn(c##F), s2=__float2half2_rn(s##F), ns2=__hneg2(s2); \
    _Pragma("unroll") for (int j=0;j<16;j++){ if (j&(BIT)) continue; ry_h(h[j],h[j|(BIT)],c2,s2,ns2);} }
#define RYH32(BIT, CC, SS) { const __half2 c2=__float2half2_rn(CC), s2=__float2half2_rn(SS), ns2=__hneg2(s2); \
    _Pragma("unroll") for (int j=0;j<32;j++){ if (j&(BIT)) continue; ry_h(h[j],h[j|(BIT)],c2,s2,ns2);} }

// ---------------- P1: full generation + layer2(- (0->15),Rz2(f15)) + Ry3(1..12)
__global__ __launch_bounds__(512, 4) void k_all(const float* __restrict__ xg,
                                                const float* __restrict__ pg,
                                                __half2* __restrict__ st)
{
    __shared__ __half2 tile[8192];   // 32 KB
    __shared__ float cA[16], sA[16], cB[16], sB[16], cC[16], sC[16], phz1[16], phz2[16];
    __shared__ float2 K4[4], V[64];
    __shared__ __half2 E2Ax[16], E2Ay[16], E2Bx[8], E2By[8],
                       E2Cx[8], E2Cy[8], E2Dx[8], E2Dy[8];
    const int tid = threadIdx.x;
    const int b = blockIdx.x >> 3;
    const unsigned outer = blockIdx.x & 7u;        // f13..15 (post-fold basis)

    // ---- stage 1: angle tables
    if (tid < 16){
        int j = tid, q = 15 - j;
        float th = 0.5f*(xg[b*16+q]*PI_F + pg[q]);           // Ry1
        __sincosf(th, &sA[j], &cA[j]);
    } else if (tid < 32){
        int j = tid-16, q = 15 - j;
        float th = 0.5f*(xg[b*16+q]*PI_F + pg[32+q]);        // Ry2
        __sincosf(th, &sB[j], &cB[j]);
    } else if (tid < 48){
        int j = tid-32, q = 15 - j;
        float th = 0.5f*(xg[b*16+q]*PI_F + pg[64+q]);        // Ry3
        __sincosf(th, &sC[j], &cC[j]);
    } else if (tid < 64){
        int j = tid-48, q = 15 - j;
        phz1[j] = 0.5f*pg[16+q];                              // Rz1
    } else if (tid < 80){
        int j = tid-64, q = 15 - j;
        phz2[j] = 0.5f*pg[48+q];                              // Rz2
    }
    __syncthreads();
    // ---- stage 2a: K4 + packed Rz2 tables (R6/R8/R16-verified values)
    if (tid < 4){
        const unsigned o13=outer&1u, o14=(outer>>1)&1u, o15=(outer>>2)&1u;
        const unsigned h13=o13^o14, h14=o14^o15, h15=o15;
        const int f0b=(tid>>1)&1, f12b=tid&1;
        float Kr=0.f, Ki=0.f;
        #pragma unroll
        for (int g=0; g<8; ++g){
            const unsigned g13=g&1u, g14=(g>>1)&1u, g15=(g>>2)&1u;
            float w;
            w  = (h13==g13)? cB[13] : (h13? sB[13] : -sB[13]);
            w *= (h14==g14)? cB[14] : (h14? sB[14] : -sB[14]);
            w *= (h15==g15)? cB[15] : (h15? sB[15] : -sB[15]);
            w *= (f12b^(int)g13)?          sA[12]:cA[12];
            w *= ((int)(g13^g14))?         sA[13]:cA[13];
            w *= ((int)g14^f0b^(int)g15)?  sA[14]:cA[14];
            w *= (f0b^(int)g15)?           sA[15]:cA[15];
            float phg = (g13? phz1[13]:-phz1[13]) + (g14? phz1[14]:-phz1[14])
                      + (g15? phz1[15]:-phz1[15]);
            float sn,cs; __sincosf(phg,&sn,&cs);
            Kr += w*cs; Ki += w*sn;
        }
        K4[tid] = make_float2(Kr,Ki);
    } else if (tid>=32 && tid<48){
        const int ii = tid-32;  // Rz2 over f9..12
        float d=0.f;
        #pragma unroll
        for (int j=0;j<4;j++) d += ((ii>>j)&1)? phz2[9+j]:-phz2[9+j];
        float sn,cs; __sincosf(d,&sn,&cs);
        E2Ax[ii]=__float2half2_rn(cs);
        E2Ay[ii]=__halves2half2(__float2half(-sn), __float2half(sn));
    } else if (tid>=48 && tid<56){
        const int ii = tid-48;  // Rz2 over f6..8
        float d=0.f;
        #pragma unroll
        for (int j=0;j<3;j++) d += ((ii>>j)&1)? phz2[6+j]:-phz2[6+j];
        float sn,cs; __sincosf(d,&sn,&cs);
        E2Bx[ii]=__float2half2_rn(cs);
        E2By[ii]=__halves2half2(__float2half(-sn), __float2half(sn));
    } else if (tid>=56 && tid<64){
        const int ii = tid-56;  // Rz2 over f3..5
        float d=0.f;
        #pragma unroll
        for (int j=0;j<3;j++) d += ((ii>>j)&1)? phz2[3+j]:-phz2[3+j];
        float sn,cs; __sincosf(d,&sn,&cs);
        E2Cx[ii]=__float2half2_rn(cs);
        E2Cy[ii]=__halves2half2(__float2half(-sn), __float2half(sn));
    } else if (tid>=64 && tid<72){
        const int ii = tid-64;  // Rz2 over f0..2 + uniform f13,f14
        float d=0.f;
        #pragma unroll
        for (int j=0;j<3;j++) d += ((ii>>j)&1)? phz2[j]:-phz2[j];
        d += (outer&1u)?      phz2[13]:-phz2[13];
        d += ((outer>>1)&1u)? phz2[14]:-phz2[14];
        float sn,cs; __sincosf(d,&sn,&cs);
        E2Dx[ii]=__float2half2_rn(cs);
        E2Dy[ii]=__halves2half2(__float2half(-sn), __float2half(sn));
    }
    __syncthreads();
    // ---- stage 2b: V table (needs K4).  V[(t8<<5)|(t0<<4)|i] =
    //   G(t8,i) * cmul(D1(i), K4[(t0<<1)|i3])   [regrouped R8 gen expression]
    if (tid < 64){
        const int i  = tid & 15;
        const int t0b = (tid>>4)&1, t8b = (tid>>5)&1;
        const int i0=i&1, i1=(i>>1)&1, i2=(i>>2)&1, i3=(i>>3)&1;
        float G = ((t8b^i0)? sA[8] :cA[8])
                * ((i0^i1)?  sA[9] :cA[9])
                * ((i1^i2)?  sA[10]:cA[10])
                * ((i2^i3)?  sA[11]:cA[11]);
        float d = 0.f;
        #pragma unroll
        for (int j=0;j<4;j++) d += ((i>>j)&1)? phz1[9+j]:-phz1[9+j];
        float sn,cs; __sincosf(d,&sn,&cs);
        float2 K = K4[(t0b<<1)|i3];
        V[tid] = make_float2(G*(cs*K.x - sn*K.y), G*(cs*K.y + sn*K.x));
    }
    __syncthreads();

    const unsigned t = tid;                 // trip A: t = f0..8 (9 bits)
    __half2 h[16];
    // ---- Trip A generation via V table
    {
        float base_t = 1.0f;
        #pragma unroll
        for (int j=0;j<8;j++){
            int v = (int)(((t>>j)^(t>>(j+1)))&1u);           // b_pre[j]=f_j^f_{j+1}
            base_t *= v? sA[j]:cA[j];
        }
        float pht = 0.f;
        #pragma unroll
        for (int j=0;j<9;j++) pht += ((t>>j)&1u)? phz1[j]:-phz1[j];
        float Ey,Ex; __sincosf(pht,&Ey,&Ex);
        Ex *= base_t; Ey *= base_t;                          // Et' = base_t * e^{i*pht}
        const float2* Vb = V + ((((t>>8)&1u)<<5) | ((t&1u)<<4));
        #pragma unroll
        for (int i=0;i<16;i++){
            const float2 v = Vb[i];
            h[i] = __float22half2_rn(make_float2(Ex*v.x - Ey*v.y, Ex*v.y + Ey*v.x));
        }
    }
    // Trip A gates: i0=f9,i1=f10,i2=f11,i3=f12   (packed fp16, R16-verified)
    { const float cF=cB[9],  sF=sB[9];  RYH(1, F) }
    { const float cF=cB[10], sF=sB[10]; RYH(2, F) }
    { const float cF=cB[11], sF=sB[11]; RYH(4, F) }
    { const float cF=cB[12], sF=sB[12]; RYH(8, F) }
    if (outer & 1u){  // CN2(13->12): ctrl f13=o13 (uniform), tgt i3
        #pragma unroll
        for (int j=0;j<16;j++){ if (j&8) continue; __half2 tm=h[j]; h[j]=h[j|8]; h[j|8]=tm; }
    }
    #pragma unroll
    for (int j=0;j<16;j++){ if (j&4) continue; if ((j>>3)&1){ __half2 tm=h[j]; h[j]=h[j|4]; h[j|4]=tm; } } // (12->11)
    #pragma unroll
    for (int j=0;j<16;j++){ if (j&2) continue; if ((j>>2)&1){ __half2 tm=h[j]; h[j]=h[j|2]; h[j|2]=tm; } } // (11->10)
    #pragma unroll
    for (int j=0;j<16;j++){ if (j&1) continue; if ((j>>1)&1){ __half2 tm=h[j]; h[j]=h[j|1]; h[j|1]=tm; } } // (10->9)
    #pragma unroll
    for (int i=0;i<16;i++) h[i] = crot_h(h[i], E2Ax[i], E2Ay[i]);   // Rz2(f9..12)
    { const float cF=cC[10], sF=sC[10]; RYH(2, F) }
    { const float cF=cC[11], sF=sC[11]; RYH(4, F) }
    { const float cF=cC[12], sF=sC[12]; RYH(8, F) }
    // ---- transpose A -> B
    #pragma unroll
    for (int i=0;i<16;i++) tile[swz(t | ((unsigned)i<<9))] = h[i];
    __syncthreads();
    #pragma unroll
    for (int i=0;i<16;i++) h[i] = tile[swz((t&63u) | ((unsigned)i<<6) | ((t>>6)<<10))];
    // Trip B: i0=f6,i1=f7,i2=f8,i3=f9 ; t&63=f0..5, t>>6=f10..12
    { const float cF=cB[6], sF=sB[6]; RYH(1, F) }
    { const float cF=cB[7], sF=sB[7]; RYH(2, F) }
    { const float cF=cB[8], sF=sB[8]; RYH(4, F) }
    #pragma unroll
    for (int j=0;j<16;j++){ if (j&4) continue; if ((j>>3)&1){ __half2 tm=h[j]; h[j]=h[j|4]; h[j|4]=tm; } } // (9->8)
    #pragma unroll
    for (int j=0;j<16;j++){ if (j&2) continue; if ((j>>2)&1){ __half2 tm=h[j]; h[j]=h[j|2]; h[j|2]=tm; } } // (8->7)
    #pragma unroll
    for (int j=0;j<16;j++){ if (j&1) continue; if ((j>>1)&1){ __half2 tm=h[j]; h[j]=h[j|1]; h[j|1]=tm; } } // (7->6)
    #pragma unroll
    for (int i=0;i<16;i++) h[i] = crot_h(h[i], E2Bx[i&7], E2By[i&7]);  // Rz2(f6..8)
    { const float cF=cC[7], sF=sC[7]; RYH(2, F) }
    { const float cF=cC[8], sF=sC[8]; RYH(4, F) }
    { const float cF=cC[9], sF=sC[9]; RYH(8, F) }
    // ---- transpose B -> C
    #pragma unroll
    for (int i=0;i<16;i++) tile[swz((t&63u) | ((unsigned)i<<6) | ((t>>6)<<10))] = h[i];
    __syncthreads();
    #pragma unroll
    for (int i=0;i<16;i++) h[i] = tile[swz((t&7u) | ((unsigned)i<<3) | ((t>>3)<<7))];
    // Trip C: i0=f3,i1=f4,i2=f5,i3=f6 ; t&7=f0..2, t>>3=f7..12
    { const float cF=cB[3], sF=sB[3]; RYH(1, F) }
    { const float cF=cB[4], sF=sB[4]; RYH(2, F) }
    { const float cF=cB[5], sF=sB[5]; RYH(4, F) }
    #pragma unroll
    for (int j=0;j<16;j++){ if (j&4) continue; if ((j>>3)&1){ __half2 tm=h[j]; h[j]=h[j|4]; h[j|4]=tm; } } // (6->5)
    #pragma unroll
    for (int j=0;j<16;j++){ if (j&2) continue; if ((j>>2)&1){ __half2 tm=h[j]; h[j]=h[j|2]; h[j|2]=tm; } } // (5->4)
    #pragma unroll
    for (int j=0;j<16;j++){ if (j&1) continue; if ((j>>1)&1){ __half2 tm=h[j]; h[j]=h[j|1]; h[j|1]=tm; } } // (4->3)
    #pragma unroll
    for (int i=0;i<16;i++) h[i] = crot_h(h[i], E2Cx[i&7], E2Cy[i&7]);  // Rz2(f3..5)
    { const float cF=cC[4], sF=sC[4]; RYH(2, F) }
    { const float cF=cC[5], sF=sC[5]; RYH(4, F) }
    { const float cF=cC[6], sF=sC[6]; RYH(8, F) }
    // ---- transpose C -> D
    #pragma unroll
    for (int i=0;i<16;i++) tile[swz((t&7u) | ((unsigned)i<<3) | ((t>>3)<<7))] = h[i];
    __syncthreads();
    #pragma unroll
    for (int i=0;i<16;i++) h[i] = tile[swz((unsigned)i | (t<<4))];
    // Trip D: i0=f0,i1=f1,i2=f2,i3=f3 ; t=f4..12
    { const float cF=cB[0], sF=sB[0]; RYH(1, F) }
    { const float cF=cB[1], sF=sB[1]; RYH(2, F) }
    { const float cF=cB[2], sF=sB[2]; RYH(4, F) }
    #pragma unroll
    for (int j=0;j<16;j++){ if (j&4) continue; if ((j>>3)&1){ __half2 tm=h[j]; h[j]=h[j|4]; h[j|4]=tm; } } // (3->2)
    #pragma unroll
    for (int j=0;j<16;j++){ if (j&2) continue; if ((j>>2)&1){ __half2 tm=h[j]; h[j]=h[j|2]; h[j|2]=tm; } } // (2->1)
    #pragma unroll
    for (int j=0;j<16;j++){ if (j&1) continue; if ((j>>1)&1){ __half2 tm=h[j]; h[j]=h[j|1]; h[j|1]=tm; } } // (1->0)
    #pragma unroll
    for (int i=0;i<16;i++) h[i] = crot_h(h[i], E2Dx[i&7], E2Dy[i&7]);  // Rz2(f0..2,f13,f14)
    { const float cF=cC[1], sF=sC[1]; RYH(2, F) }
    { const float cF=cC[2], sF=sC[2]; RYH(4, F) }
    { const float cF=cC[3], sF=sC[3]; RYH(8, F) }
    // ---- DIRECT store from trip-D layout: f = i | (t<<4) | (outer<<13),
    //      i=0..15 consecutive -> 64 B contiguous per lane, 4 adjacent uint4.
    {
        __half2* hp = st + ((size_t)b<<16) + ((t<<4) | (outer<<13));
        #pragma unroll
        for (int u=0;u<4;u++){
            __half2 hv[4];
            hv[0]=h[4*u+0]; hv[1]=h[4*u+1]; hv[2]=h[4*u+2]; hv[3]=h[4*u+3];
            *reinterpret_cast<uint4*>(hp + 4*u) = *reinterpret_cast<uint4*>(hv);
        }
    }
}

// ---------------- P2 k_fin (B-type, outer = f10..12, READ, no LDS tile)
// R17-verbatim: packed fp16 gates, f32 accumulation.
__global__ __launch_bounds__(256) void k_fin(const float* __restrict__ xg,
                                             const float* __restrict__ pg,
                                             const __half2* __restrict__ st,
                                             float* __restrict__ outg)
{
    __shared__ float cN[16], sN[16];
    __shared__ float snp, csp;
    __shared__ float red[4][3];
    const int tid = threadIdx.x;
    const int b = blockIdx.x >> 3;
    const unsigned outer = blockIdx.x & 7u;        // f bits 10..12
    if (tid < 16){
        int j=tid, q=15-j;
        float th = 0.5f*(xg[b*16+q]*PI_F + pg[64 + q]);      // Ry3
        float s,c; __sincosf(th,&s,&c);
        cN[j]=c; sN[j]=s;
    }
    if (tid==16){ float phi = 0.5f*pg[48 + 0]; float s,c; __sincosf(phi,&s,&c); snp=s; csp=c; }
    __syncthreads();
    const unsigned t = tid;
    const __half2* sp = st + ((size_t)b<<16);
    __half2 h[32];
    #pragma unroll
    for (int u=0;u<8;u++){
        unsigned fb = (t<<2) | (outer<<10) | ((unsigned)u<<13);
        uint4 raw = *reinterpret_cast<const uint4*>(sp + fb);
        const __half2* hv = reinterpret_cast<const __half2*>(&raw);
        h[4*u+0]=hv[0]; h[4*u+1]=hv[1]; h[4*u+2]=hv[2]; h[4*u+3]=hv[3];
    }
    // CN2(0->15): ctrl f0 = i0, tgt f15 = i4 (exact swap)
    #pragma unroll
    for (int j=0;j<32;j++){ if (j&16) continue; if (j&1){ __half2 tm=h[j]; h[j]=h[j|16]; h[j|16]=tm; } }
    // Rz2(f15): angle = +-phi by i4   (packed)
    {
        const __half2 wxx = __float2half2_rn(csp);
        const __half2 wyp = __halves2half2(__float2half(-snp), __float2half(snp));   // +phi
        const __half2 wym = __halves2half2(__float2half( snp), __float2half(-snp));  // -phi
        #pragma unroll
        for (int j=0;j<32;j++) h[j] = crot_h(h[j], wxx, (j&16)? wyp : wym);
    }
    // Ry3(f0)=bit1 ; Ry3(f13)=bit4 ; Ry3(f14)=bit8 ; Ry3(f15)=bit16  (packed)
    RYH32(1,  cN[0],  sN[0])
    RYH32(4,  cN[13], sN[13])
    RYH32(8,  cN[14], sN[14])
    RYH32(16, cN[15], sN[15])
    // measurement (f32 accumulation)
    const int pto = (__popc(t) + __popc(outer)) & 1;   // parity(f2..f12)
    float v0=0.f, v1=0.f, v2=0.f;
    #pragma unroll
    for (int i=0;i<32;i++){
        const int i0=i&1, i1=(i>>1)&1, i2=(i>>2)&1, i3=(i>>3)&1, i4=(i>>4)&1;
        const float2 a = __half22float2(h[i]);
        const float pr = a.x*a.x + a.y*a.y;
        v0 += (i0^i1^i2^i3^pto)? -pr : pr;   // parity(f0..f14)
        v1 += (i3^i4)?           -pr : pr;   // f14^f15
        v2 += (i2^i3^i4)?        -pr : pr;   // f13^f14^f15
    }
    #pragma unroll
    for (int off=32; off>0; off>>=1){
        v0 += __shfl_down(v0, off);
        v1 += __shfl_down(v1, off);
        v2 += __shfl_down(v2, off);
    }
    const int wv = tid>>6, ln = tid&63;
    if (ln==0){ red[wv][0]=v0; red[wv][1]=v1; red[wv][2]=v2; }
    __syncthreads();
    if (tid<3){
        float s = red[0][tid]+red[1][tid]+red[2][tid]+red[3][tid];
        atomicAdd(&outg[b*3+tid], s);
    }
}

extern "C" void kernel_launch(void* const* d_in, const int* in_sizes, int n_in,
                              void* d_out, int out_size, void* d_ws, size_t ws_size,
                              hipStream_t stream)
{
    const float* x = (const float*)d_in[0];
    const float* params = (const float*)d_in[1];
    float* out = (float*)d_out;
    __half2* st = (__half2*)d_ws;
    const int B = in_sizes[0] / 16;

    hipMemsetAsync(d_out, 0, (size_t)out_size*sizeof(float), stream);

    const size_t per = (size_t)65536 * sizeof(__half2);  // 256 KB per batch element
    int chunk = (int)(ws_size / per);
    if (chunk > 512) chunk = 512;                        // 512 elem = 134 MB < L3
    if (chunk < 1) chunk = 1;
    if (chunk > B) chunk = B;
    for (int b0=0; b0<B; b0+=chunk){
        const int nb = (B-b0 < chunk) ? (B-b0) : chunk;
        const float* xb = x + (size_t)b0*16;
        float* ob = out + (size_t)b0*3;
        hipLaunchKernelGGL(k_all, dim3(nb*8), dim3(512), 0, stream, xb, params, st);
        hipLaunchKernelGGL(k_fin, dim3(nb*8), dim3(256), 0, stream, xb, params, st, ob);
    }
}